// Round 1
// baseline (370.903 us; speedup 1.0000x reference)
//
#include <hip/hip_runtime.h>
#include <hip/hip_bf16.h>
#include <stdint.h>

// Problem constants
#define BB   2
#define SS   2048
#define HHH  2048
#define NHH  16
#define HDD  128
#define MTOT 4096   // BB*SS

typedef __bf16 bf16x8 __attribute__((ext_vector_type(8)));
typedef float  f32x4  __attribute__((ext_vector_type(4)));

#define MFMA16(a, b, c) __builtin_amdgcn_mfma_f32_16x16x32_bf16((a), (b), (c), 0, 0, 0)

__device__ __forceinline__ unsigned short f2bf(float f) {
    union { float f; unsigned u; } v; v.f = f;
    unsigned r = v.u + 0x7FFFu + ((v.u >> 16) & 1u);   // RNE
    return (unsigned short)(r >> 16);
}

// async global->LDS, 16B per lane. LDS dest is wave-uniform base + lane*16.
__device__ __forceinline__ void gload16(const void* src, void* lds) {
    __builtin_amdgcn_global_load_lds(
        (__attribute__((address_space(1))) void*)src,
        (__attribute__((address_space(3))) void*)lds,
        16, 0, 0);
}

// ---------------- cast f32 -> bf16 (vectorized) ----------------
__global__ void cast_f32_bf16(const float* __restrict__ in,
                              unsigned short* __restrict__ out, int n) {
    int i = (blockIdx.x * blockDim.x + threadIdx.x) * 4;
    int stride = gridDim.x * blockDim.x * 4;
    for (; i < n; i += stride) {
        float4 v = *(const float4*)(in + i);
        ushort4 o;
        o.x = f2bf(v.x); o.y = f2bf(v.y); o.z = f2bf(v.z); o.w = f2bf(v.w);
        *(ushort4*)(out + i) = o;
    }
}

// ---------------- transpose + cast: W (K x N f32) -> Wt (N x K bf16) ----------------
__global__ void transpose_cast(const float* __restrict__ in,
                               unsigned short* __restrict__ out) {
    __shared__ float tile[32][33];
    int c0 = blockIdx.x * 32, r0 = blockIdx.y * 32;
    int tx = threadIdx.x, ty = threadIdx.y;   // (32, 8)
    #pragma unroll
    for (int i = 0; i < 32; i += 8)
        tile[ty + i][tx] = in[(size_t)(r0 + ty + i) * HHH + c0 + tx];
    __syncthreads();
    #pragma unroll
    for (int i = 0; i < 32; i += 8)
        out[(size_t)(c0 + ty + i) * HHH + r0 + tx] = f2bf(tile[tx][ty + i]);
}

// ---------------- GEMM: C[M,N] = A[M,K] @ Bt[N,K]^T + bias ----------------
// MODE 0: bf16 row-major out. MODE 1: bf16 out transposed per head (for V).
// MODE 2: f32 row-major out.
template<int MODE>
__global__ __launch_bounds__(256, 2) void gemm_bf16(
    const unsigned short* __restrict__ A,
    const unsigned short* __restrict__ Bt,
    const float* __restrict__ bias,
    void* __restrict__ Cout,
    int M, int N, int K)
{
    __shared__ __align__(16) unsigned char sm[16384]; // A tile [128][32] @0, B tile @8192
    const int tid = threadIdx.x;
    const int wv = tid >> 6, ln = tid & 63;
    const int g = ln >> 4, r = ln & 15;
    const int wr = wv >> 1, wc = wv & 1;
    const int m0 = blockIdx.x * 128, n0 = blockIdx.y * 128;

    // staging: each wave stages 2 chunks (1KB each) of A and of B.
    // LDS linear; source pre-swizzled: logical granule = phys ^ ((row>>1)&3).
    size_t srcA[2], srcB[2];
    int ldsA[2], ldsB[2];
    #pragma unroll
    for (int i = 0; i < 2; ++i) {
        int ch = wv * 2 + i;
        int o = ch * 1024 + ln * 16;
        int row = o >> 6;
        int gl = ((o >> 4) & 3) ^ ((row >> 1) & 3);
        ldsA[i] = ch * 1024;
        ldsB[i] = 8192 + ch * 1024;
        srcA[i] = (size_t)(m0 + row) * K + gl * 8;
        srcB[i] = (size_t)(n0 + row) * K + gl * 8;
    }

    f32x4 acc[4][4];
    #pragma unroll
    for (int i = 0; i < 4; ++i)
        #pragma unroll
        for (int j = 0; j < 4; ++j)
            acc[i][j] = (f32x4){0.f, 0.f, 0.f, 0.f};

    for (int kt = 0; kt < K; kt += 32) {
        __syncthreads();   // prior tile fully consumed
        #pragma unroll
        for (int i = 0; i < 2; ++i) {
            gload16(A + srcA[i] + kt, sm + ldsA[i]);
            gload16(Bt + srcB[i] + kt, sm + ldsB[i]);
        }
        __syncthreads();   // drains vmcnt before barrier

        bf16x8 af[4], bfr[4];
        #pragma unroll
        for (int t = 0; t < 4; ++t) {
            int rowa = wr * 64 + t * 16 + r;
            int pha = g ^ ((rowa >> 1) & 3);
            af[t] = *(const bf16x8*)(sm + rowa * 64 + pha * 16);
            int rowb = wc * 64 + t * 16 + r;
            int phb = g ^ ((rowb >> 1) & 3);
            bfr[t] = *(const bf16x8*)(sm + 8192 + rowb * 64 + phb * 16);
        }
        #pragma unroll
        for (int mt = 0; mt < 4; ++mt)
            #pragma unroll
            for (int nt = 0; nt < 4; ++nt)
                acc[mt][nt] = MFMA16(af[mt], bfr[nt], acc[mt][nt]);
    }

    // epilogue: C/D layout col = lane&15, row = 4*(lane>>4)+reg
    #pragma unroll
    for (int mt = 0; mt < 4; ++mt) {
        #pragma unroll
        for (int nt = 0; nt < 4; ++nt) {
            int col = n0 + wc * 64 + nt * 16 + r;
            float bvv = bias[col];
            f32x4 a = acc[mt][nt];
            int mrow = m0 + wr * 64 + mt * 16 + g * 4;
            if (MODE == 0) {
                #pragma unroll
                for (int q = 0; q < 4; ++q)
                    ((unsigned short*)Cout)[(size_t)(mrow + q) * N + col] = f2bf(a[q] + bvv);
            } else if (MODE == 2) {
                #pragma unroll
                for (int q = 0; q < 4; ++q)
                    ((float*)Cout)[(size_t)(mrow + q) * N + col] = a[q] + bvv;
            } else {
                // V transposed per head: Vt[(b*2048 + n)][s], 4 consecutive s -> 8B store
                int b = mrow >> 11, s0x = mrow & 2047;
                ushort4 o;
                o.x = f2bf(a[0] + bvv); o.y = f2bf(a[1] + bvv);
                o.z = f2bf(a[2] + bvv); o.w = f2bf(a[3] + bvv);
                *(ushort4*)((unsigned short*)Cout + ((size_t)(b * 2048 + col)) * 2048 + s0x) = o;
            }
        }
    }
}

// ---------------- flash attention ----------------
// Q,K: (4096, 2048) bf16 row-major; V: transposed per head (4096 rows = b*2048 + h*128 + d, 2048 cols = s)
// O: (4096, 2048) bf16. 4 waves x 32 q-rows per block; KB=64 keys per iter.
__global__ __launch_bounds__(256, 2) void attn_fwd(
    const unsigned short* __restrict__ Q,
    const unsigned short* __restrict__ K,
    const unsigned short* __restrict__ V,
    const float* __restrict__ mask,
    unsigned short* __restrict__ O)
{
    __shared__ __align__(16) unsigned char sm[49152]; // K[64][128]@0, Vt[128][64]@16384, P per-wave @32768
    const int tid = threadIdx.x, wv = tid >> 6, ln = tid & 63;
    const int g = ln >> 4, r = ln & 15;
    const int qb = blockIdx.x & 15;
    const int bh = blockIdx.x >> 4;
    const int h = bh & 15, b = bh >> 4;

    const size_t rowQ0 = (size_t)(b * 2048 + qb * 128 + wv * 32);

    // Q fragments in registers (A-operand): row = lane&15, k = (lane>>4)*8+j
    bf16x8 qf[2][4];
    #pragma unroll
    for (int rt = 0; rt < 2; ++rt)
        #pragma unroll
        for (int ks = 0; ks < 4; ++ks)
            qf[rt][ks] = *(const bf16x8*)(Q + (rowQ0 + rt * 16 + r) * 2048 + h * 128 + ks * 32 + g * 8);

    f32x4 acc[2][8];
    #pragma unroll
    for (int i = 0; i < 2; ++i)
        #pragma unroll
        for (int j = 0; j < 8; ++j)
            acc[i][j] = (f32x4){0.f, 0.f, 0.f, 0.f};
    float mr[2][4], lr[2][4];
    #pragma unroll
    for (int i = 0; i < 2; ++i)
        #pragma unroll
        for (int j = 0; j < 4; ++j) { mr[i][j] = -3.0e38f; lr[i][j] = 0.f; }

    const float scale = 0.08838834764831845f;  // 1/sqrt(128)
    const float* mb = mask + b * 2048;
    unsigned char* const pl = sm + 32768 + wv * 4096;

    for (int kb = 0; kb < SS; kb += 64) {
        __syncthreads();
        // stage K tile [64][128] and Vt tile [128][64], XOR-swizzled via source
        #pragma unroll
        for (int i = 0; i < 4; ++i) {
            int ch = wv * 4 + i;
            int o = ch * 1024 + ln * 16;
            { int row = o >> 8; int gl = ((o >> 4) & 15) ^ (row & 7);
              gload16(K + (size_t)(b * 2048 + kb + row) * 2048 + h * 128 + gl * 8, sm + ch * 1024); }
            { int d = o >> 7; int gl = ((o >> 4) & 7) ^ (d & 7);
              gload16(V + (size_t)(b * 2048 + h * 128 + d) * 2048 + kb + gl * 8, sm + 16384 + ch * 1024); }
        }
        __syncthreads();

        // S = Q K^T (B-fragment from K_lds rows = keys, swizzled read)
        float sv[2][4][4];
        #pragma unroll
        for (int ct = 0; ct < 4; ++ct) {
            f32x4 s0 = (f32x4){0.f,0.f,0.f,0.f}, s1 = s0;
            int row = ct * 16 + r;
            #pragma unroll
            for (int ks = 0; ks < 4; ++ks) {
                int ph = (ks * 4 + g) ^ (row & 7);
                bf16x8 kf = *(const bf16x8*)(sm + row * 256 + ph * 16);
                s0 = MFMA16(qf[0][ks], kf, s0);
                s1 = MFMA16(qf[1][ks], kf, s1);
            }
            float mv = mb[kb + ct * 16 + r];
            #pragma unroll
            for (int q = 0; q < 4; ++q) {
                sv[0][ct][q] = s0[q] * scale + mv;
                sv[1][ct][q] = s1[q] * scale + mv;
            }
        }

        // online softmax: row owned by 16 lanes (same g), 4 rows/lane (regs)
        #pragma unroll
        for (int rt = 0; rt < 2; ++rt) {
            #pragma unroll
            for (int q = 0; q < 4; ++q) {
                float bmx = fmaxf(fmaxf(sv[rt][0][q], sv[rt][1][q]),
                                  fmaxf(sv[rt][2][q], sv[rt][3][q]));
                #pragma unroll
                for (int off = 1; off < 16; off <<= 1)
                    bmx = fmaxf(bmx, __shfl_xor(bmx, off));
                float nm = fmaxf(mr[rt][q], bmx);
                float alpha = __expf(mr[rt][q] - nm);
                mr[rt][q] = nm;
                float rs = 0.f;
                #pragma unroll
                for (int ct = 0; ct < 4; ++ct) {
                    float p = __expf(sv[rt][ct][q] - nm);
                    sv[rt][ct][q] = p;
                    rs += p;
                }
                #pragma unroll
                for (int off = 1; off < 16; off <<= 1)
                    rs += __shfl_xor(rs, off);
                lr[rt][q] = lr[rt][q] * alpha + rs;
                #pragma unroll
                for (int dt = 0; dt < 8; ++dt)
                    acc[rt][dt][q] *= alpha;
            }
        }

        // write P to per-wave LDS (C layout -> rows), swizzled
        #pragma unroll
        for (int rt = 0; rt < 2; ++rt)
            #pragma unroll
            for (int ct = 0; ct < 4; ++ct)
                #pragma unroll
                for (int q = 0; q < 4; ++q) {
                    int row = rt * 16 + g * 4 + q;
                    int cb = (ct * 16 + r) * 2;
                    *(unsigned short*)(pl + row * 128 + (cb ^ ((row & 7) << 4))) = f2bf(sv[rt][ct][q]);
                }

        // O += P V   (A = P from LDS, B = Vt from LDS)
        bf16x8 pf[2][2];
        #pragma unroll
        for (int rt = 0; rt < 2; ++rt)
            #pragma unroll
            for (int ks = 0; ks < 2; ++ks) {
                int pr = rt * 16 + r;
                int ph = (ks * 4 + g) ^ (pr & 7);
                pf[rt][ks] = *(const bf16x8*)(pl + pr * 128 + ph * 16);
            }
        #pragma unroll
        for (int dt = 0; dt < 8; ++dt) {
            int d = dt * 16 + r;
            f32x4 a0 = acc[0][dt], a1 = acc[1][dt];
            #pragma unroll
            for (int ks = 0; ks < 2; ++ks) {
                int ph = (ks * 4 + g) ^ (d & 7);
                bf16x8 vf = *(const bf16x8*)(sm + 16384 + d * 128 + ph * 16);
                a0 = MFMA16(pf[0][ks], vf, a0);
                a1 = MFMA16(pf[1][ks], vf, a1);
            }
            acc[0][dt] = a0; acc[1][dt] = a1;
        }
    }

    // epilogue: divide by l, store bf16
    #pragma unroll
    for (int rt = 0; rt < 2; ++rt)
        #pragma unroll
        for (int dt = 0; dt < 8; ++dt)
            #pragma unroll
            for (int q = 0; q < 4; ++q) {
                float v = acc[rt][dt][q] / lr[rt][q];
                size_t row = rowQ0 + rt * 16 + g * 4 + q;
                O[row * 2048 + h * 128 + dt * 16 + r] = f2bf(v);
            }
}

// ---------------- host launch ----------------
extern "C" void kernel_launch(void* const* d_in, const int* in_sizes, int n_in,
                              void* d_out, int out_size, void* d_ws, size_t ws_size,
                              hipStream_t stream)
{
    (void)in_sizes; (void)n_in; (void)out_size; (void)ws_size;
    const float* x    = (const float*)d_in[0];
    const float* mask = (const float*)d_in[1];
    const float* Wq   = (const float*)d_in[2];
    const float* bq   = (const float*)d_in[3];
    const float* Wk   = (const float*)d_in[4];
    const float* bk   = (const float*)d_in[5];
    const float* Wv   = (const float*)d_in[6];
    const float* bv   = (const float*)d_in[7];
    const float* Wo   = (const float*)d_in[8];
    const float* bo   = (const float*)d_in[9];
    float* out = (float*)d_out;

    char* ws = (char*)d_ws;
    unsigned short* xb  = (unsigned short*)(ws);                        // 16 MB
    unsigned short* Wqt = (unsigned short*)(ws + (16u << 20));          //  8 MB
    unsigned short* Wkt = (unsigned short*)(ws + (24u << 20));          //  8 MB
    unsigned short* Wvt = (unsigned short*)(ws + (32u << 20));          //  8 MB
    unsigned short* Wot = (unsigned short*)(ws + (40u << 20));          //  8 MB
    unsigned short* Qb  = (unsigned short*)(ws + (48u << 20));          // 16 MB
    unsigned short* Kb  = (unsigned short*)(ws + (64u << 20));          // 16 MB
    unsigned short* Vtb = (unsigned short*)(ws + (80u << 20));          // 16 MB
    unsigned short* Ab  = (unsigned short*)(ws + (16u << 20));          // 16 MB, reuses Wqt/Wkt (dead by then)

    cast_f32_bf16<<<2048, 256, 0, stream>>>(x, xb, MTOT * HHH);
    dim3 tb(32, 8), tg(64, 64);
    transpose_cast<<<tg, tb, 0, stream>>>(Wq, Wqt);
    transpose_cast<<<tg, tb, 0, stream>>>(Wk, Wkt);
    transpose_cast<<<tg, tb, 0, stream>>>(Wv, Wvt);
    transpose_cast<<<tg, tb, 0, stream>>>(Wo, Wot);

    dim3 gg(MTOT / 128, HHH / 128);  // (32, 16)
    gemm_bf16<0><<<gg, 256, 0, stream>>>(xb, Wqt, bq, Qb,  MTOT, HHH, HHH);
    gemm_bf16<0><<<gg, 256, 0, stream>>>(xb, Wkt, bk, Kb,  MTOT, HHH, HHH);
    gemm_bf16<1><<<gg, 256, 0, stream>>>(xb, Wvt, bv, Vtb, MTOT, HHH, HHH);

    attn_fwd<<<BB * NHH * (SS / 128), 256, 0, stream>>>(Qb, Kb, Vtb, mask, Ab);

    gemm_bf16<2><<<gg, 256, 0, stream>>>(Ab, Wot, bo, out, MTOT, HHH, HHH);
}

// Round 2
// 317.516 us; speedup vs baseline: 1.1681x; 1.1681x over previous
//
#include <hip/hip_runtime.h>
#include <hip/hip_bf16.h>
#include <stdint.h>

// Problem constants
#define BB   2
#define SS   2048
#define HHH  2048
#define NHH  16
#define HDD  128
#define MTOT 4096   // BB*SS

typedef __bf16 bf16x8 __attribute__((ext_vector_type(8)));
typedef float  f32x4  __attribute__((ext_vector_type(4)));

#define MFMA16(a, b, c) __builtin_amdgcn_mfma_f32_16x16x32_bf16((a), (b), (c), 0, 0, 0)

__device__ __forceinline__ unsigned short f2bf(float f) {
    union { float f; unsigned u; } v; v.f = f;
    unsigned r = v.u + 0x7FFFu + ((v.u >> 16) & 1u);   // RNE
    return (unsigned short)(r >> 16);
}

__device__ __forceinline__ unsigned packbf(float a, float b) {
    union { __bf16 h[2]; unsigned u; } p;
    p.h[0] = (__bf16)a; p.h[1] = (__bf16)b;
    return p.u;
}

// async global->LDS, 16B per lane. LDS dest is wave-uniform base + lane*16.
__device__ __forceinline__ void gload16(const void* src, void* lds) {
    __builtin_amdgcn_global_load_lds(
        (__attribute__((address_space(1))) void*)src,
        (__attribute__((address_space(3))) void*)lds,
        16, 0, 0);
}

// ---------------- cast f32 -> bf16 (vectorized) ----------------
__global__ void cast_f32_bf16(const float* __restrict__ in,
                              unsigned short* __restrict__ out, int n) {
    int i = (blockIdx.x * blockDim.x + threadIdx.x) * 4;
    int stride = gridDim.x * blockDim.x * 4;
    for (; i < n; i += stride) {
        float4 v = *(const float4*)(in + i);
        ushort4 o;
        o.x = f2bf(v.x); o.y = f2bf(v.y); o.z = f2bf(v.z); o.w = f2bf(v.w);
        *(ushort4*)(out + i) = o;
    }
}

// ---------------- transpose + cast: W (K x N f32) -> Wt (N x K bf16) ----------------
__global__ void transpose_cast(const float* __restrict__ in,
                               unsigned short* __restrict__ out) {
    __shared__ float tile[32][33];
    int c0 = blockIdx.x * 32, r0 = blockIdx.y * 32;
    int tx = threadIdx.x, ty = threadIdx.y;   // (32, 8)
    #pragma unroll
    for (int i = 0; i < 32; i += 8)
        tile[ty + i][tx] = in[(size_t)(r0 + ty + i) * HHH + c0 + tx];
    __syncthreads();
    #pragma unroll
    for (int i = 0; i < 32; i += 8)
        out[(size_t)(c0 + ty + i) * HHH + r0 + tx] = f2bf(tile[tx][ty + i]);
}

// ---------------- GEMM: C[M,N] = A[M,K] @ Bt[N,K]^T + bias ----------------
// MODE 0: bf16 row-major out. MODE 1: bf16 out transposed per head (for V).
// MODE 2: f32 row-major out.
template<int MODE>
__global__ __launch_bounds__(256, 2) void gemm_bf16(
    const unsigned short* __restrict__ A,
    const unsigned short* __restrict__ Bt,
    const float* __restrict__ bias,
    void* __restrict__ Cout,
    int M, int N, int K)
{
    __shared__ __align__(16) unsigned char sm[16384]; // A tile [128][32] @0, B tile @8192
    const int tid = threadIdx.x;
    const int wv = tid >> 6, ln = tid & 63;
    const int g = ln >> 4, r = ln & 15;
    const int wr = wv >> 1, wc = wv & 1;
    const int m0 = blockIdx.x * 128, n0 = blockIdx.y * 128;

    size_t srcA[2], srcB[2];
    int ldsA[2], ldsB[2];
    #pragma unroll
    for (int i = 0; i < 2; ++i) {
        int ch = wv * 2 + i;
        int o = ch * 1024 + ln * 16;
        int row = o >> 6;
        int gl = ((o >> 4) & 3) ^ ((row >> 1) & 3);
        ldsA[i] = ch * 1024;
        ldsB[i] = 8192 + ch * 1024;
        srcA[i] = (size_t)(m0 + row) * K + gl * 8;
        srcB[i] = (size_t)(n0 + row) * K + gl * 8;
    }

    f32x4 acc[4][4];
    #pragma unroll
    for (int i = 0; i < 4; ++i)
        #pragma unroll
        for (int j = 0; j < 4; ++j)
            acc[i][j] = (f32x4){0.f, 0.f, 0.f, 0.f};

    for (int kt = 0; kt < K; kt += 32) {
        __syncthreads();
        #pragma unroll
        for (int i = 0; i < 2; ++i) {
            gload16(A + srcA[i] + kt, sm + ldsA[i]);
            gload16(Bt + srcB[i] + kt, sm + ldsB[i]);
        }
        __syncthreads();

        bf16x8 af[4], bfr[4];
        #pragma unroll
        for (int t = 0; t < 4; ++t) {
            int rowa = wr * 64 + t * 16 + r;
            int pha = g ^ ((rowa >> 1) & 3);
            af[t] = *(const bf16x8*)(sm + rowa * 64 + pha * 16);
            int rowb = wc * 64 + t * 16 + r;
            int phb = g ^ ((rowb >> 1) & 3);
            bfr[t] = *(const bf16x8*)(sm + 8192 + rowb * 64 + phb * 16);
        }
        #pragma unroll
        for (int mt = 0; mt < 4; ++mt)
            #pragma unroll
            for (int nt = 0; nt < 4; ++nt)
                acc[mt][nt] = MFMA16(af[mt], bfr[nt], acc[mt][nt]);
    }

    #pragma unroll
    for (int mt = 0; mt < 4; ++mt) {
        #pragma unroll
        for (int nt = 0; nt < 4; ++nt) {
            int col = n0 + wc * 64 + nt * 16 + r;
            float bvv = bias[col];
            f32x4 a = acc[mt][nt];
            int mrow = m0 + wr * 64 + mt * 16 + g * 4;
            if (MODE == 0) {
                #pragma unroll
                for (int q = 0; q < 4; ++q)
                    ((unsigned short*)Cout)[(size_t)(mrow + q) * N + col] = f2bf(a[q] + bvv);
            } else if (MODE == 2) {
                #pragma unroll
                for (int q = 0; q < 4; ++q)
                    ((float*)Cout)[(size_t)(mrow + q) * N + col] = a[q] + bvv;
            } else {
                int b = mrow >> 11, s0x = mrow & 2047;
                ushort4 o;
                o.x = f2bf(a[0] + bvv); o.y = f2bf(a[1] + bvv);
                o.z = f2bf(a[2] + bvv); o.w = f2bf(a[3] + bvv);
                *(ushort4*)((unsigned short*)Cout + ((size_t)(b * 2048 + col)) * 2048 + s0x) = o;
            }
        }
    }
}

// ---------------- flash attention (swapped-QK^T, in-register P, dbuf K/V) ----------------
// Q,K: (4096, 2048) bf16 row-major; V: transposed per head (rows = b*2048 + h*128 + d, cols = s)
// O: (4096, 2048) bf16. 4 waves x 32 q-rows per block; KB=64 keys per iter.
__global__ __launch_bounds__(256, 2) void attn_fwd(
    const unsigned short* __restrict__ Q,
    const unsigned short* __restrict__ K,
    const unsigned short* __restrict__ V,
    const float* __restrict__ mask,
    unsigned short* __restrict__ O)
{
    __shared__ __align__(16) unsigned char sm[65536]; // dbuf: {K[64][128], Vt[128][64]} x2
    const int tid = threadIdx.x, wv = tid >> 6, ln = tid & 63;
    const int g = ln >> 4, r = ln & 15;

    // XCD-bijective swizzle: 64 consecutive logical blocks (4 full heads) per XCD
    const int bid = blockIdx.x;
    const int lb = (bid & 7) * 64 + (bid >> 3);
    const int qb = lb & 15;
    const int bh = lb >> 4;
    const int h = bh & 15, b = bh >> 4;

    const size_t rowQ0 = (size_t)(b * 2048 + qb * 128 + wv * 32);
    const float SCL2 = 0.08838834764831845f * 1.4426950408889634f; // scale * log2(e)
    const float L2E  = 1.4426950408889634f;

    // staging address precompute (same swizzles as round-1, proven)
    unsigned srcK[4], srcV[4];
    int ldsK[4], ldsV[4];
    #pragma unroll
    for (int i = 0; i < 4; ++i) {
        int ch = wv * 4 + i;
        int o = ch * 1024 + ln * 16;
        { int row = o >> 8; int gl = ((o >> 4) & 15) ^ (row & 7);
          srcK[i] = (unsigned)((b * 2048 + row) * 2048 + h * 128 + gl * 8);
          ldsK[i] = ch * 1024; }
        { int d = o >> 7; int gl = ((o >> 4) & 7) ^ (d & 7);
          srcV[i] = (unsigned)((b * 2048 + h * 128 + d) * 2048 + gl * 8);
          ldsV[i] = 16384 + ch * 1024; }
    }

    // stage tile 0 into buffer 0 (issue before Q loads so both overlap)
    #pragma unroll
    for (int i = 0; i < 4; ++i) {
        gload16(K + srcK[i], sm + ldsK[i]);
        gload16(V + srcV[i], sm + ldsV[i]);
    }

    // Q fragments (B-operand): col = lane&15 = qrow, k = g*8+j
    bf16x8 qf[2][4];
    #pragma unroll
    for (int rtq = 0; rtq < 2; ++rtq)
        #pragma unroll
        for (int ks = 0; ks < 4; ++ks)
            qf[rtq][ks] = *(const bf16x8*)(Q + (rowQ0 + rtq * 16 + r) * 2048 + h * 128 + ks * 32 + g * 8);

    f32x4 acc[2][8];
    #pragma unroll
    for (int i = 0; i < 2; ++i)
        #pragma unroll
        for (int j = 0; j < 8; ++j)
            acc[i][j] = (f32x4){0.f, 0.f, 0.f, 0.f};
    float mr[2] = {-3.0e38f, -3.0e38f};   // running max, log2 domain, row = rtq*16 + r
    float lr[2] = {0.f, 0.f};

    const float* mb = mask + b * 2048;
    const int L0 = ((g & 1) * 2) * 16 + r;   // P-shuffle source lanes
    const int L1 = L0 + 16;

    int cur = 0;
    __syncthreads();   // tile 0 ready (drains vmcnt)

    for (int kb = 0; kb < SS; kb += 64) {
        // issue next-tile staging first (overlaps this tile's compute)
        if (kb + 64 < SS) {
            const unsigned char* dst = sm + (cur ^ 1) * 32768;
            int ko = (kb + 64) * 2048;
            #pragma unroll
            for (int i = 0; i < 4; ++i) {
                gload16(K + srcK[i] + ko, (void*)(dst + ldsK[i]));
                gload16(V + srcV[i] + (kb + 64), (void*)(dst + ldsV[i]));
            }
        }
        const unsigned char* Kt = sm + cur * 32768;
        const unsigned char* Vt = Kt + 16384;

        // mask (prescaled to log2 domain), issued early
        f32x4 mvv[4];
        #pragma unroll
        for (int ct = 0; ct < 4; ++ct)
            mvv[ct] = *(const f32x4*)(mb + kb + ct * 16 + g * 4);

        // S^T = K Q^T : frag[ct][rtq], lane holds S[qrow=rtq*16+r][key=ct*16+g*4+q]
        f32x4 sfr[4][2];
        #pragma unroll
        for (int ct = 0; ct < 4; ++ct) { sfr[ct][0] = (f32x4){0,0,0,0}; sfr[ct][1] = (f32x4){0,0,0,0}; }
        __builtin_amdgcn_s_setprio(1);
        #pragma unroll
        for (int ct = 0; ct < 4; ++ct) {
            int row = ct * 16 + r;
            #pragma unroll
            for (int ks = 0; ks < 4; ++ks) {
                int ph = (ks * 4 + g) ^ (row & 7);
                bf16x8 kf = *(const bf16x8*)(Kt + row * 256 + ph * 16);
                sfr[ct][0] = MFMA16(kf, qf[0][ks], sfr[ct][0]);
                sfr[ct][1] = MFMA16(kf, qf[1][ks], sfr[ct][1]);
            }
        }
        __builtin_amdgcn_s_setprio(0);

        // scale + mask in log2 domain
        #pragma unroll
        for (int ct = 0; ct < 4; ++ct)
            #pragma unroll
            for (int rtq = 0; rtq < 2; ++rtq)
                #pragma unroll
                for (int q = 0; q < 4; ++q)
                    sfr[ct][rtq][q] = sfr[ct][rtq][q] * SCL2 + mvv[ct][q] * L2E;

        // row max (in-lane tree over 16, then cross-g)
        float mt[2];
        #pragma unroll
        for (int rtq = 0; rtq < 2; ++rtq) {
            float a0 = fmaxf(fmaxf(sfr[0][rtq][0], sfr[0][rtq][1]), fmaxf(sfr[0][rtq][2], sfr[0][rtq][3]));
            float a1 = fmaxf(fmaxf(sfr[1][rtq][0], sfr[1][rtq][1]), fmaxf(sfr[1][rtq][2], sfr[1][rtq][3]));
            float a2 = fmaxf(fmaxf(sfr[2][rtq][0], sfr[2][rtq][1]), fmaxf(sfr[2][rtq][2], sfr[2][rtq][3]));
            float a3 = fmaxf(fmaxf(sfr[3][rtq][0], sfr[3][rtq][1]), fmaxf(sfr[3][rtq][2], sfr[3][rtq][3]));
            float m = fmaxf(fmaxf(a0, a1), fmaxf(a2, a3));
            m = fmaxf(m, __shfl_xor(m, 16));
            m = fmaxf(m, __shfl_xor(m, 32));
            mt[rtq] = m;
        }

        // defer-max: skip rescale when tile max doesn't exceed running max + 8 (log2)
        float alpha[2] = {1.f, 1.f};
        int allskip = __all((mt[0] <= mr[0] + 8.f) && (mt[1] <= mr[1] + 8.f));
        if (!allskip) {
            #pragma unroll
            for (int rtq = 0; rtq < 2; ++rtq) {
                float nm = fmaxf(mr[rtq], mt[rtq]);
                alpha[rtq] = __builtin_amdgcn_exp2f(mr[rtq] - nm);
                mr[rtq] = nm;
            }
            // broadcast alpha to acc rows (row = g*4+q) and rescale O
            #pragma unroll
            for (int rtq = 0; rtq < 2; ++rtq)
                #pragma unroll
                for (int q = 0; q < 4; ++q) {
                    float ar = __shfl(alpha[rtq], g * 4 + q);
                    #pragma unroll
                    for (int dt = 0; dt < 8; ++dt)
                        acc[rtq][dt][q] *= ar;
                }
        }

        // P = exp2(S - m), row sum, l update
        #pragma unroll
        for (int rtq = 0; rtq < 2; ++rtq) {
            float rs = 0.f;
            #pragma unroll
            for (int ct = 0; ct < 4; ++ct)
                #pragma unroll
                for (int q = 0; q < 4; ++q) {
                    float p = __builtin_amdgcn_exp2f(sfr[ct][rtq][q] - mr[rtq]);
                    sfr[ct][rtq][q] = p;
                    rs += p;
                }
            rs += __shfl_xor(rs, 16);
            rs += __shfl_xor(rs, 32);
            lr[rtq] = lr[rtq] * alpha[rtq] + rs;
        }

        // pack P to bf16 pairs: plo = keys(g*4+0,1), phi = keys(g*4+2,3)
        unsigned plo[4][2], phi[4][2];
        #pragma unroll
        for (int ct = 0; ct < 4; ++ct)
            #pragma unroll
            for (int rtq = 0; rtq < 2; ++rtq) {
                plo[ct][rtq] = packbf(sfr[ct][rtq][0], sfr[ct][rtq][1]);
                phi[ct][rtq] = packbf(sfr[ct][rtq][2], sfr[ct][rtq][3]);
            }

        // redistribute P to A-fragment layout via shuffles:
        // pf[rtq][ks] word w: from lane L=( (g&1)*2 + (w>>1) )*16 + r,
        // variable (w&1? phi:plo)[2ks + (g>>1)][rtq]
        bf16x8 pf[2][2];
        #pragma unroll
        for (int rtq = 0; rtq < 2; ++rtq)
            #pragma unroll
            for (int ks = 0; ks < 2; ++ks) {
                union { unsigned w[4]; bf16x8 v; } u;
                #pragma unroll
                for (int w = 0; w < 4; ++w) {
                    int L = (w < 2) ? L0 : L1;
                    unsigned a = (w & 1) ? phi[2 * ks][rtq]     : plo[2 * ks][rtq];
                    unsigned c = (w & 1) ? phi[2 * ks + 1][rtq] : plo[2 * ks + 1][rtq];
                    unsigned va = (unsigned)__shfl((int)a, L);
                    unsigned vc = (unsigned)__shfl((int)c, L);
                    u.w[w] = (g & 2) ? vc : va;
                }
                pf[rtq][ks] = u.v;
            }

        // O += P V
        __builtin_amdgcn_s_setprio(1);
        #pragma unroll
        for (int dt = 0; dt < 8; ++dt) {
            int d = dt * 16 + r;
            f32x4 a0 = acc[0][dt], a1 = acc[1][dt];
            #pragma unroll
            for (int ks = 0; ks < 2; ++ks) {
                int ph = (ks * 4 + g) ^ (d & 7);
                bf16x8 vf = *(const bf16x8*)(Vt + d * 128 + ph * 16);
                a0 = MFMA16(pf[0][ks], vf, a0);
                a1 = MFMA16(pf[1][ks], vf, a1);
            }
            acc[0][dt] = a0; acc[1][dt] = a1;
        }
        __builtin_amdgcn_s_setprio(0);

        __syncthreads();   // next tile staged & this tile fully consumed
        cur ^= 1;
    }

    // epilogue: O row = rtq*16 + g*4 + q needs l of that row (broadcast from lane g*4+q)
    #pragma unroll
    for (int rtq = 0; rtq < 2; ++rtq) {
        float linv[4];
        #pragma unroll
        for (int q = 0; q < 4; ++q)
            linv[q] = 1.f / __shfl(lr[rtq], g * 4 + q);
        #pragma unroll
        for (int dt = 0; dt < 8; ++dt)
            #pragma unroll
            for (int q = 0; q < 4; ++q) {
                float v = acc[rtq][dt][q] * linv[q];
                size_t row = rowQ0 + rtq * 16 + g * 4 + q;
                O[row * 2048 + h * 128 + dt * 16 + r] = f2bf(v);
            }
    }
}

// ---------------- host launch ----------------
extern "C" void kernel_launch(void* const* d_in, const int* in_sizes, int n_in,
                              void* d_out, int out_size, void* d_ws, size_t ws_size,
                              hipStream_t stream)
{
    (void)in_sizes; (void)n_in; (void)out_size; (void)ws_size;
    const float* x    = (const float*)d_in[0];
    const float* mask = (const float*)d_in[1];
    const float* Wq   = (const float*)d_in[2];
    const float* bq   = (const float*)d_in[3];
    const float* Wk   = (const float*)d_in[4];
    const float* bk   = (const float*)d_in[5];
    const float* Wv   = (const float*)d_in[6];
    const float* bv   = (const float*)d_in[7];
    const float* Wo   = (const float*)d_in[8];
    const float* bo   = (const float*)d_in[9];
    float* out = (float*)d_out;

    char* ws = (char*)d_ws;
    unsigned short* xb  = (unsigned short*)(ws);                        // 16 MB
    unsigned short* Wqt = (unsigned short*)(ws + (16u << 20));          //  8 MB
    unsigned short* Wkt = (unsigned short*)(ws + (24u << 20));          //  8 MB
    unsigned short* Wvt = (unsigned short*)(ws + (32u << 20));          //  8 MB
    unsigned short* Wot = (unsigned short*)(ws + (40u << 20));          //  8 MB
    unsigned short* Qb  = (unsigned short*)(ws + (48u << 20));          // 16 MB
    unsigned short* Kb  = (unsigned short*)(ws + (64u << 20));          // 16 MB
    unsigned short* Vtb = (unsigned short*)(ws + (80u << 20));          // 16 MB
    unsigned short* Ab  = (unsigned short*)(ws + (16u << 20));          // 16 MB, reuses Wqt/Wkt (dead by then)

    cast_f32_bf16<<<2048, 256, 0, stream>>>(x, xb, MTOT * HHH);
    dim3 tb(32, 8), tg(64, 64);
    transpose_cast<<<tg, tb, 0, stream>>>(Wq, Wqt);
    transpose_cast<<<tg, tb, 0, stream>>>(Wk, Wkt);
    transpose_cast<<<tg, tb, 0, stream>>>(Wv, Wvt);
    transpose_cast<<<tg, tb, 0, stream>>>(Wo, Wot);

    dim3 gg(MTOT / 128, HHH / 128);  // (32, 16)
    gemm_bf16<0><<<gg, 256, 0, stream>>>(xb, Wqt, bq, Qb,  MTOT, HHH, HHH);
    gemm_bf16<0><<<gg, 256, 0, stream>>>(xb, Wkt, bk, Kb,  MTOT, HHH, HHH);
    gemm_bf16<1><<<gg, 256, 0, stream>>>(xb, Wvt, bv, Vtb, MTOT, HHH, HHH);

    attn_fwd<<<BB * NHH * (SS / 128), 256, 0, stream>>>(Qb, Kb, Vtb, mask, Ab);

    gemm_bf16<2><<<gg, 256, 0, stream>>>(Ab, Wot, bo, out, MTOT, HHH, HHH);
}

// Round 3
// 312.972 us; speedup vs baseline: 1.1851x; 1.0145x over previous
//
#include <hip/hip_runtime.h>
#include <hip/hip_bf16.h>
#include <stdint.h>

// Problem constants
#define BB   2
#define SS   2048
#define HHH  2048
#define NHH  16
#define HDD  128
#define MTOT 4096   // BB*SS

typedef __bf16 bf16x8 __attribute__((ext_vector_type(8)));
typedef float  f32x4  __attribute__((ext_vector_type(4)));
typedef float  f32x16 __attribute__((ext_vector_type(16)));

#define MFMA16(a, b, c) __builtin_amdgcn_mfma_f32_16x16x32_bf16((a), (b), (c), 0, 0, 0)
#define MFMA32(a, b, c) __builtin_amdgcn_mfma_f32_32x32x16_bf16((a), (b), (c), 0, 0, 0)

__device__ __forceinline__ unsigned short f2bf(float f) {
    union { float f; unsigned u; } v; v.f = f;
    unsigned r = v.u + 0x7FFFu + ((v.u >> 16) & 1u);   // RNE
    return (unsigned short)(r >> 16);
}

__device__ __forceinline__ unsigned packbf(float a, float b) {
    union { __bf16 h[2]; unsigned u; } p;
    p.h[0] = (__bf16)a; p.h[1] = (__bf16)b;
    return p.u;
}

// async global->LDS, 16B per lane. LDS dest is wave-uniform base + lane*16.
__device__ __forceinline__ void gload16(const void* src, void* lds) {
    __builtin_amdgcn_global_load_lds(
        (__attribute__((address_space(1))) void*)src,
        (__attribute__((address_space(3))) void*)lds,
        16, 0, 0);
}

// ---------------- cast f32 -> bf16 (vectorized) ----------------
__global__ void cast_f32_bf16(const float* __restrict__ in,
                              unsigned short* __restrict__ out, int n) {
    int i = (blockIdx.x * blockDim.x + threadIdx.x) * 4;
    int stride = gridDim.x * blockDim.x * 4;
    for (; i < n; i += stride) {
        float4 v = *(const float4*)(in + i);
        ushort4 o;
        o.x = f2bf(v.x); o.y = f2bf(v.y); o.z = f2bf(v.z); o.w = f2bf(v.w);
        *(ushort4*)(out + i) = o;
    }
}

// ---------------- transpose + cast: W (K x N f32) -> Wt (N x K bf16) ----------------
__global__ void transpose_cast(const float* __restrict__ in,
                               unsigned short* __restrict__ out) {
    __shared__ float tile[32][33];
    int c0 = blockIdx.x * 32, r0 = blockIdx.y * 32;
    int tx = threadIdx.x, ty = threadIdx.y;   // (32, 8)
    #pragma unroll
    for (int i = 0; i < 32; i += 8)
        tile[ty + i][tx] = in[(size_t)(r0 + ty + i) * HHH + c0 + tx];
    __syncthreads();
    #pragma unroll
    for (int i = 0; i < 32; i += 8)
        out[(size_t)(c0 + ty + i) * HHH + r0 + tx] = f2bf(tile[tx][ty + i]);
}

// ---------------- GEMM: C[M,N] = A[M,K] @ Bt[N,K]^T + bias ----------------
template<int MODE>
__global__ __launch_bounds__(256, 2) void gemm_bf16(
    const unsigned short* __restrict__ A,
    const unsigned short* __restrict__ Bt,
    const float* __restrict__ bias,
    void* __restrict__ Cout,
    int M, int N, int K)
{
    __shared__ __align__(16) unsigned char sm[16384];
    const int tid = threadIdx.x;
    const int wv = tid >> 6, ln = tid & 63;
    const int g = ln >> 4, r = ln & 15;
    const int wr = wv >> 1, wc = wv & 1;
    const int m0 = blockIdx.x * 128, n0 = blockIdx.y * 128;

    size_t srcA[2], srcB[2];
    int ldsA[2], ldsB[2];
    #pragma unroll
    for (int i = 0; i < 2; ++i) {
        int ch = wv * 2 + i;
        int o = ch * 1024 + ln * 16;
        int row = o >> 6;
        int gl = ((o >> 4) & 3) ^ ((row >> 1) & 3);
        ldsA[i] = ch * 1024;
        ldsB[i] = 8192 + ch * 1024;
        srcA[i] = (size_t)(m0 + row) * K + gl * 8;
        srcB[i] = (size_t)(n0 + row) * K + gl * 8;
    }

    f32x4 acc[4][4];
    #pragma unroll
    for (int i = 0; i < 4; ++i)
        #pragma unroll
        for (int j = 0; j < 4; ++j)
            acc[i][j] = (f32x4){0.f, 0.f, 0.f, 0.f};

    for (int kt = 0; kt < K; kt += 32) {
        __syncthreads();
        #pragma unroll
        for (int i = 0; i < 2; ++i) {
            gload16(A + srcA[i] + kt, sm + ldsA[i]);
            gload16(Bt + srcB[i] + kt, sm + ldsB[i]);
        }
        __syncthreads();

        bf16x8 af[4], bfr[4];
        #pragma unroll
        for (int t = 0; t < 4; ++t) {
            int rowa = wr * 64 + t * 16 + r;
            int pha = g ^ ((rowa >> 1) & 3);
            af[t] = *(const bf16x8*)(sm + rowa * 64 + pha * 16);
            int rowb = wc * 64 + t * 16 + r;
            int phb = g ^ ((rowb >> 1) & 3);
            bfr[t] = *(const bf16x8*)(sm + 8192 + rowb * 64 + phb * 16);
        }
        #pragma unroll
        for (int mt = 0; mt < 4; ++mt)
            #pragma unroll
            for (int nt = 0; nt < 4; ++nt)
                acc[mt][nt] = MFMA16(af[mt], bfr[nt], acc[mt][nt]);
    }

    #pragma unroll
    for (int mt = 0; mt < 4; ++mt) {
        #pragma unroll
        for (int nt = 0; nt < 4; ++nt) {
            int col = n0 + wc * 64 + nt * 16 + r;
            float bvv = bias[col];
            f32x4 a = acc[mt][nt];
            int mrow = m0 + wr * 64 + mt * 16 + g * 4;
            if (MODE == 0) {
                #pragma unroll
                for (int q = 0; q < 4; ++q)
                    ((unsigned short*)Cout)[(size_t)(mrow + q) * N + col] = f2bf(a[q] + bvv);
            } else if (MODE == 2) {
                #pragma unroll
                for (int q = 0; q < 4; ++q)
                    ((float*)Cout)[(size_t)(mrow + q) * N + col] = a[q] + bvv;
            } else {
                int b = mrow >> 11, s0x = mrow & 2047;
                ushort4 o;
                o.x = f2bf(a[0] + bvv); o.y = f2bf(a[1] + bvv);
                o.z = f2bf(a[2] + bvv); o.w = f2bf(a[3] + bvv);
                *(ushort4*)((unsigned short*)Cout + ((size_t)(b * 2048 + col)) * 2048 + s0x) = o;
            }
        }
    }
}

// ---------------- flash attention, 32x32 MFMA ----------------
// Q,K: (4096,2048) bf16 row-major; V: transposed per head (rows = b*2048 + h*128 + d, cols = s)
// 4 waves x 32 q-rows; KVBLK=64; dbuf K[64][128]+Vt[128][64] per buffer (32KB), x2.
// Swapped QK^T: S^T = mfma32(K, Q): lane holds one q-row (col=lane&31),
// keys (reg&3)+8*(reg>>2)+4*hi per kb2*32. PV: O^T = mfma32(V^T, P^T).
__global__ __launch_bounds__(256, 2) void attn_fwd(
    const unsigned short* __restrict__ Q,
    const unsigned short* __restrict__ K,
    const unsigned short* __restrict__ V,
    const float* __restrict__ mask,
    unsigned short* __restrict__ O)
{
    __shared__ __align__(16) unsigned char sm[65536];
    const int tid = threadIdx.x, wv = tid >> 6, ln = tid & 63;
    const int hi = ln >> 5, qr = ln & 31;

    // XCD-bijective swizzle (512 blocks = 8 XCD x 64)
    const int bid = blockIdx.x;
    const int lb = (bid & 7) * 64 + (bid >> 3);
    const int qb = lb & 15;
    const int bh = lb >> 4;
    const int h = bh & 15, b = bh >> 4;

    const size_t rowQ0 = (size_t)(b * 2048 + qb * 128 + wv * 32);
    const float SCL2 = 0.08838834764831845f * 1.4426950408889634f; // scale*log2e
    const float L2E  = 1.4426950408889634f;

    // staging precompute (identical to round-2, proven)
    unsigned srcK[4], srcV[4];
    int ldsK[4], ldsV[4];
    #pragma unroll
    for (int i = 0; i < 4; ++i) {
        int ch = wv * 4 + i;
        int o = ch * 1024 + ln * 16;
        { int row = o >> 8; int gl = ((o >> 4) & 15) ^ (row & 7);
          srcK[i] = (unsigned)((b * 2048 + row) * 2048 + h * 128 + gl * 8);
          ldsK[i] = ch * 1024; }
        { int d = o >> 7; int gl = ((o >> 4) & 7) ^ (d & 7);
          srcV[i] = (unsigned)((b * 2048 + h * 128 + d) * 2048 + gl * 8);
          ldsV[i] = 16384 + ch * 1024; }
    }

    // stage tile 0 into buffer 0
    #pragma unroll
    for (int i = 0; i < 4; ++i) {
        gload16(K + srcK[i], sm + ldsK[i]);
        gload16(V + srcV[i], sm + ldsV[i]);
    }

    // Q fragments (B-operand): col = qr, k = hi*8+j, 8 k-steps of 16
    bf16x8 qf[8];
    #pragma unroll
    for (int ks = 0; ks < 8; ++ks)
        qf[ks] = *(const bf16x8*)(Q + (rowQ0 + qr) * 2048 + h * 128 + ks * 16 + hi * 8);

    f32x16 acc[4];
    #pragma unroll
    for (int i = 0; i < 4; ++i)
        #pragma unroll
        for (int j = 0; j < 16; ++j)
            acc[i][j] = 0.f;
    float mr = -3.0e38f, lr = 0.f;   // per-lane: q-row = qr

    const float* mb = mask + b * 2048;
    int cur = 0;
    __syncthreads();   // tile 0 ready

    for (int kb = 0; kb < SS; kb += 64) {
        if (kb + 64 < SS) {
            const unsigned char* dst = sm + (cur ^ 1) * 32768;
            int ko = (kb + 64) * 2048;
            #pragma unroll
            for (int i = 0; i < 4; ++i) {
                gload16(K + srcK[i] + ko, (void*)(dst + ldsK[i]));
                gload16(V + srcV[i] + (kb + 64), (void*)(dst + ldsV[i]));
            }
        }
        const unsigned char* Kt = sm + cur * 32768;
        const unsigned char* Vt = Kt + 16384;

        // mask values for this lane's keys: key = kb2*32 + rg*8 + hi*4 + q4
        f32x4 mk[2][4];
        #pragma unroll
        for (int kb2 = 0; kb2 < 2; ++kb2)
            #pragma unroll
            for (int rg = 0; rg < 4; ++rg)
                mk[kb2][rg] = *(const f32x4*)(mb + kb + kb2 * 32 + rg * 8 + hi * 4);

        // S^T = K Q^T
        f32x16 sf0, sf1;
        #pragma unroll
        for (int j = 0; j < 16; ++j) { sf0[j] = 0.f; sf1[j] = 0.f; }
        __builtin_amdgcn_s_setprio(1);
        #pragma unroll
        for (int ks = 0; ks < 8; ++ks) {
            int row0 = qr, row1 = 32 + qr;
            int s0 = ((2 * ks + hi) ^ (row0 & 7));
            int s1 = ((2 * ks + hi) ^ (row1 & 7));
            bf16x8 kf0 = *(const bf16x8*)(Kt + row0 * 256 + s0 * 16);
            bf16x8 kf1 = *(const bf16x8*)(Kt + row1 * 256 + s1 * 16);
            sf0 = MFMA32(kf0, qf[ks], sf0);
            sf1 = MFMA32(kf1, qf[ks], sf1);
        }
        __builtin_amdgcn_s_setprio(0);

        // scale + mask (log2 domain)
        float sv[2][16];
        #pragma unroll
        for (int reg = 0; reg < 16; ++reg) {
            sv[0][reg] = sf0[reg] * SCL2 + mk[0][reg >> 2][reg & 3] * L2E;
            sv[1][reg] = sf1[reg] * SCL2 + mk[1][reg >> 2][reg & 3] * L2E;
        }

        // row max: in-lane over 32, then cross-hi
        float m01 = fmaxf(sv[0][0], sv[1][0]);
        #pragma unroll
        for (int reg = 1; reg < 16; ++reg)
            m01 = fmaxf(m01, fmaxf(sv[0][reg], sv[1][reg]));
        float mt = fmaxf(m01, __shfl_xor(m01, 32));

        // defer-max
        float alpha = 1.f;
        int allskip = __all(mt <= mr + 8.f);
        if (!allskip) {
            float nm = fmaxf(mr, mt);
            alpha = __builtin_amdgcn_exp2f(mr - nm);
            mr = nm;
            #pragma unroll
            for (int dblk = 0; dblk < 4; ++dblk)
                #pragma unroll
                for (int reg = 0; reg < 16; ++reg)
                    acc[dblk][reg] *= alpha;
        }

        // P = exp2(S - m), row sum
        float rs = 0.f;
        #pragma unroll
        for (int kb2 = 0; kb2 < 2; ++kb2)
            #pragma unroll
            for (int reg = 0; reg < 16; ++reg) {
                float p = __builtin_amdgcn_exp2f(sv[kb2][reg] - mr);
                sv[kb2][reg] = p;
                rs += p;
            }
        rs += __shfl_xor(rs, 32);
        lr = lr * alpha + rs;

        // pack P and build PV B-fragments.
        // held key offset in 16-block kb16: (rg&1)*8 + 4*hi + q4, rg = 2*(kb16&1)+half
        // frag words: hi=0: {Wh0_0, Wh0_1, y0, y1}; hi=1: {y0, y1, Wh1_0, Wh1_1}
        // where y = shfl_xor(Wh[1-hi], 32)
        bf16x8 pfr[4];
        #pragma unroll
        for (int kb16 = 0; kb16 < 4; ++kb16) {
            const int kb2 = kb16 >> 1, i2 = kb16 & 1;
            float* pv = sv[kb2];
            unsigned W00 = packbf(pv[(2*i2+0)*4 + 0], pv[(2*i2+0)*4 + 1]);
            unsigned W01 = packbf(pv[(2*i2+0)*4 + 2], pv[(2*i2+0)*4 + 3]);
            unsigned W10 = packbf(pv[(2*i2+1)*4 + 0], pv[(2*i2+1)*4 + 1]);
            unsigned W11 = packbf(pv[(2*i2+1)*4 + 2], pv[(2*i2+1)*4 + 3]);
            unsigned v0 = hi ? W00 : W10;
            unsigned v1 = hi ? W01 : W11;
            unsigned y0 = (unsigned)__shfl_xor((int)v0, 32);
            unsigned y1 = (unsigned)__shfl_xor((int)v1, 32);
            union { unsigned w[4]; bf16x8 v; } u;
            u.w[0] = hi ? y0  : W00;
            u.w[1] = hi ? y1  : W01;
            u.w[2] = hi ? W10 : y0;
            u.w[3] = hi ? W11 : y1;
            pfr[kb16] = u.v;
        }

        // O^T += V^T P^T
        __builtin_amdgcn_s_setprio(1);
        #pragma unroll
        for (int dblk = 0; dblk < 4; ++dblk) {
            int d = dblk * 32 + qr;
            f32x16 a = acc[dblk];
            #pragma unroll
            for (int kb16 = 0; kb16 < 4; ++kb16) {
                int s = ((2 * kb16 + hi) ^ (d & 7));
                bf16x8 vf = *(const bf16x8*)(Vt + d * 128 + s * 16);
                a = MFMA32(vf, pfr[kb16], a);
            }
            acc[dblk] = a;
        }
        __builtin_amdgcn_s_setprio(0);

        __syncthreads();
        cur ^= 1;
    }

    // epilogue: O[qrow][d], d = dblk*32 + rg*8 + 4*hi + q4; per-lane 1/l
    float linv = 1.f / lr;
    unsigned short* orow = O + (rowQ0 + qr) * 2048 + h * 128;
    #pragma unroll
    for (int dblk = 0; dblk < 4; ++dblk)
        #pragma unroll
        for (int rg = 0; rg < 4; ++rg) {
            float v0 = acc[dblk][rg * 4 + 0] * linv;
            float v1 = acc[dblk][rg * 4 + 1] * linv;
            float v2 = acc[dblk][rg * 4 + 2] * linv;
            float v3 = acc[dblk][rg * 4 + 3] * linv;
            uint2 o;
            o.x = packbf(v0, v1);
            o.y = packbf(v2, v3);
            *(uint2*)(orow + dblk * 32 + rg * 8 + hi * 4) = o;
        }
}

// ---------------- host launch ----------------
extern "C" void kernel_launch(void* const* d_in, const int* in_sizes, int n_in,
                              void* d_out, int out_size, void* d_ws, size_t ws_size,
                              hipStream_t stream)
{
    (void)in_sizes; (void)n_in; (void)out_size; (void)ws_size;
    const float* x    = (const float*)d_in[0];
    const float* mask = (const float*)d_in[1];
    const float* Wq   = (const float*)d_in[2];
    const float* bq   = (const float*)d_in[3];
    const float* Wk   = (const float*)d_in[4];
    const float* bk   = (const float*)d_in[5];
    const float* Wv   = (const float*)d_in[6];
    const float* bv   = (const float*)d_in[7];
    const float* Wo   = (const float*)d_in[8];
    const float* bo   = (const float*)d_in[9];
    float* out = (float*)d_out;

    char* ws = (char*)d_ws;
    unsigned short* xb  = (unsigned short*)(ws);                        // 16 MB
    unsigned short* Wqt = (unsigned short*)(ws + (16u << 20));          //  8 MB
    unsigned short* Wkt = (unsigned short*)(ws + (24u << 20));          //  8 MB
    unsigned short* Wvt = (unsigned short*)(ws + (32u << 20));          //  8 MB
    unsigned short* Wot = (unsigned short*)(ws + (40u << 20));          //  8 MB
    unsigned short* Qb  = (unsigned short*)(ws + (48u << 20));          // 16 MB
    unsigned short* Kb  = (unsigned short*)(ws + (64u << 20));          // 16 MB
    unsigned short* Vtb = (unsigned short*)(ws + (80u << 20));          // 16 MB
    unsigned short* Ab  = (unsigned short*)(ws + (16u << 20));          // 16 MB, reuses Wqt/Wkt

    cast_f32_bf16<<<2048, 256, 0, stream>>>(x, xb, MTOT * HHH);
    dim3 tb(32, 8), tg(64, 64);
    transpose_cast<<<tg, tb, 0, stream>>>(Wq, Wqt);
    transpose_cast<<<tg, tb, 0, stream>>>(Wk, Wkt);
    transpose_cast<<<tg, tb, 0, stream>>>(Wv, Wvt);
    transpose_cast<<<tg, tb, 0, stream>>>(Wo, Wot);

    dim3 gg(MTOT / 128, HHH / 128);  // (32, 16)
    gemm_bf16<0><<<gg, 256, 0, stream>>>(xb, Wqt, bq, Qb,  MTOT, HHH, HHH);
    gemm_bf16<0><<<gg, 256, 0, stream>>>(xb, Wkt, bk, Kb,  MTOT, HHH, HHH);
    gemm_bf16<1><<<gg, 256, 0, stream>>>(xb, Wvt, bv, Vtb, MTOT, HHH, HHH);

    attn_fwd<<<BB * NHH * (SS / 128), 256, 0, stream>>>(Qb, Kb, Vtb, mask, Ab);

    gemm_bf16<2><<<gg, 256, 0, stream>>>(Ab, Wot, bo, out, MTOT, HHH, HHH);
}

// Round 4
// 309.294 us; speedup vs baseline: 1.1992x; 1.0119x over previous
//
#include <hip/hip_runtime.h>
#include <hip/hip_bf16.h>
#include <stdint.h>

// Problem constants
#define BB   2
#define SS   2048
#define HHH  2048
#define NHH  16
#define HDD  128
#define MTOT 4096   // BB*SS

typedef __bf16 bf16x8 __attribute__((ext_vector_type(8)));
typedef float  f32x4  __attribute__((ext_vector_type(4)));
typedef float  f32x16 __attribute__((ext_vector_type(16)));

#define MFMA16(a, b, c) __builtin_amdgcn_mfma_f32_16x16x32_bf16((a), (b), (c), 0, 0, 0)
#define MFMA32(a, b, c) __builtin_amdgcn_mfma_f32_32x32x16_bf16((a), (b), (c), 0, 0, 0)

__device__ __forceinline__ unsigned short f2bf(float f) {
    union { float f; unsigned u; } v; v.f = f;
    unsigned r = v.u + 0x7FFFu + ((v.u >> 16) & 1u);   // RNE
    return (unsigned short)(r >> 16);
}

__device__ __forceinline__ unsigned packbf(float a, float b) {
    union { __bf16 h[2]; unsigned u; } p;
    p.h[0] = (__bf16)a; p.h[1] = (__bf16)b;
    return p.u;
}

// v_permlane32_swap_b32: a' = [a.lo32, b.lo32], b' = [a.hi32, b.hi32]
__device__ __forceinline__ void pswap(unsigned &a, unsigned &b) {
    asm("v_permlane32_swap_b32 %0, %1" : "+v"(a), "+v"(b));
}

// cross-half (lane ^ 32) pair: returns {own-half view, other-half view}
__device__ __forceinline__ float2 xswap(float x) {
    unsigned a = __builtin_bit_cast(unsigned, x);
    unsigned b;
    asm("v_mov_b32 %0, %1" : "=v"(b) : "v"(a));   // force distinct register
    asm("v_permlane32_swap_b32 %0, %1" : "+v"(a), "+v"(b));
    return make_float2(__builtin_bit_cast(float, a), __builtin_bit_cast(float, b));
}

// async global->LDS, 16B per lane. LDS dest is wave-uniform base + lane*16.
__device__ __forceinline__ void gload16(const void* src, void* lds) {
    __builtin_amdgcn_global_load_lds(
        (__attribute__((address_space(1))) void*)src,
        (__attribute__((address_space(3))) void*)lds,
        16, 0, 0);
}

// ---------------- cast f32 -> bf16 (vectorized) ----------------
__global__ void cast_f32_bf16(const float* __restrict__ in,
                              unsigned short* __restrict__ out, int n) {
    int i = (blockIdx.x * blockDim.x + threadIdx.x) * 4;
    int stride = gridDim.x * blockDim.x * 4;
    for (; i < n; i += stride) {
        float4 v = *(const float4*)(in + i);
        ushort4 o;
        o.x = f2bf(v.x); o.y = f2bf(v.y); o.z = f2bf(v.z); o.w = f2bf(v.w);
        *(ushort4*)(out + i) = o;
    }
}

// ---------------- transpose + cast: W (K x N f32) -> Wt (N x K bf16) ----------------
__global__ void transpose_cast(const float* __restrict__ in,
                               unsigned short* __restrict__ out) {
    __shared__ float tile[32][33];
    int c0 = blockIdx.x * 32, r0 = blockIdx.y * 32;
    int tx = threadIdx.x, ty = threadIdx.y;   // (32, 8)
    #pragma unroll
    for (int i = 0; i < 32; i += 8)
        tile[ty + i][tx] = in[(size_t)(r0 + ty + i) * HHH + c0 + tx];
    __syncthreads();
    #pragma unroll
    for (int i = 0; i < 32; i += 8)
        out[(size_t)(c0 + ty + i) * HHH + r0 + tx] = f2bf(tile[tx][ty + i]);
}

// ---------------- GEMM: C[M,N] = A[M,K] @ Bt[N,K]^T + bias ----------------
template<int MODE>
__global__ __launch_bounds__(256, 2) void gemm_bf16(
    const unsigned short* __restrict__ A,
    const unsigned short* __restrict__ Bt,
    const float* __restrict__ bias,
    void* __restrict__ Cout,
    int M, int N, int K)
{
    __shared__ __align__(16) unsigned char sm[16384];
    const int tid = threadIdx.x;
    const int wv = tid >> 6, ln = tid & 63;
    const int g = ln >> 4, r = ln & 15;
    const int wr = wv >> 1, wc = wv & 1;
    const int m0 = blockIdx.x * 128, n0 = blockIdx.y * 128;

    size_t srcA[2], srcB[2];
    int ldsA[2], ldsB[2];
    #pragma unroll
    for (int i = 0; i < 2; ++i) {
        int ch = wv * 2 + i;
        int o = ch * 1024 + ln * 16;
        int row = o >> 6;
        int gl = ((o >> 4) & 3) ^ ((row >> 1) & 3);
        ldsA[i] = ch * 1024;
        ldsB[i] = 8192 + ch * 1024;
        srcA[i] = (size_t)(m0 + row) * K + gl * 8;
        srcB[i] = (size_t)(n0 + row) * K + gl * 8;
    }

    f32x4 acc[4][4];
    #pragma unroll
    for (int i = 0; i < 4; ++i)
        #pragma unroll
        for (int j = 0; j < 4; ++j)
            acc[i][j] = (f32x4){0.f, 0.f, 0.f, 0.f};

    for (int kt = 0; kt < K; kt += 32) {
        __syncthreads();
        #pragma unroll
        for (int i = 0; i < 2; ++i) {
            gload16(A + srcA[i] + kt, sm + ldsA[i]);
            gload16(Bt + srcB[i] + kt, sm + ldsB[i]);
        }
        __syncthreads();

        bf16x8 af[4], bfr[4];
        #pragma unroll
        for (int t = 0; t < 4; ++t) {
            int rowa = wr * 64 + t * 16 + r;
            int pha = g ^ ((rowa >> 1) & 3);
            af[t] = *(const bf16x8*)(sm + rowa * 64 + pha * 16);
            int rowb = wc * 64 + t * 16 + r;
            int phb = g ^ ((rowb >> 1) & 3);
            bfr[t] = *(const bf16x8*)(sm + 8192 + rowb * 64 + phb * 16);
        }
        #pragma unroll
        for (int mt = 0; mt < 4; ++mt)
            #pragma unroll
            for (int nt = 0; nt < 4; ++nt)
                acc[mt][nt] = MFMA16(af[mt], bfr[nt], acc[mt][nt]);
    }

    #pragma unroll
    for (int mt = 0; mt < 4; ++mt) {
        #pragma unroll
        for (int nt = 0; nt < 4; ++nt) {
            int col = n0 + wc * 64 + nt * 16 + r;
            float bvv = bias[col];
            f32x4 a = acc[mt][nt];
            int mrow = m0 + wr * 64 + mt * 16 + g * 4;
            if (MODE == 0) {
                #pragma unroll
                for (int q = 0; q < 4; ++q)
                    ((unsigned short*)Cout)[(size_t)(mrow + q) * N + col] = f2bf(a[q] + bvv);
            } else if (MODE == 2) {
                #pragma unroll
                for (int q = 0; q < 4; ++q)
                    ((float*)Cout)[(size_t)(mrow + q) * N + col] = a[q] + bvv;
            } else {
                int b = mrow >> 11, s0x = mrow & 2047;
                ushort4 o;
                o.x = f2bf(a[0] + bvv); o.y = f2bf(a[1] + bvv);
                o.z = f2bf(a[2] + bvv); o.w = f2bf(a[3] + bvv);
                *(ushort4*)((unsigned short*)Cout + ((size_t)(b * 2048 + col)) * 2048 + s0x) = o;
            }
        }
    }
}

// ---------------- flash attention, 32x32 MFMA, permlane cross-half ----------------
__global__ __launch_bounds__(256, 2) void attn_fwd(
    const unsigned short* __restrict__ Q,
    const unsigned short* __restrict__ K,
    const unsigned short* __restrict__ V,
    const float* __restrict__ mask,
    unsigned short* __restrict__ O)
{
    __shared__ __align__(16) unsigned char sm[65536];
    const int tid = threadIdx.x, wv = tid >> 6, ln = tid & 63;
    const int hi = ln >> 5, qr = ln & 31;

    // XCD-bijective swizzle (512 blocks = 8 XCD x 64)
    const int bid = blockIdx.x;
    const int lb = (bid & 7) * 64 + (bid >> 3);
    const int qb = lb & 15;
    const int bh = lb >> 4;
    const int h = bh & 15, b = bh >> 4;

    const size_t rowQ0 = (size_t)(b * 2048 + qb * 128 + wv * 32);
    const float SCL2 = 0.08838834764831845f * 1.4426950408889634f; // scale*log2e
    const float L2E  = 1.4426950408889634f;

    unsigned srcK[4], srcV[4];
    int ldsK[4], ldsV[4];
    #pragma unroll
    for (int i = 0; i < 4; ++i) {
        int ch = wv * 4 + i;
        int o = ch * 1024 + ln * 16;
        { int row = o >> 8; int gl = ((o >> 4) & 15) ^ (row & 7);
          srcK[i] = (unsigned)((b * 2048 + row) * 2048 + h * 128 + gl * 8);
          ldsK[i] = ch * 1024; }
        { int d = o >> 7; int gl = ((o >> 4) & 7) ^ (d & 7);
          srcV[i] = (unsigned)((b * 2048 + h * 128 + d) * 2048 + gl * 8);
          ldsV[i] = 16384 + ch * 1024; }
    }

    // stage tile 0 into buffer 0
    #pragma unroll
    for (int i = 0; i < 4; ++i) {
        gload16(K + srcK[i], sm + ldsK[i]);
        gload16(V + srcV[i], sm + ldsV[i]);
    }

    // Q fragments (B-operand): col = qr, k = hi*8+j, 8 k-steps of 16
    bf16x8 qf[8];
    #pragma unroll
    for (int ks = 0; ks < 8; ++ks)
        qf[ks] = *(const bf16x8*)(Q + (rowQ0 + qr) * 2048 + h * 128 + ks * 16 + hi * 8);

    f32x16 acc[4];
    #pragma unroll
    for (int i = 0; i < 4; ++i)
        #pragma unroll
        for (int j = 0; j < 16; ++j)
            acc[i][j] = 0.f;
    float mr = -3.0e38f, lr = 0.f;   // per-lane: q-row = qr

    const float* mb = mask + b * 2048;
    int cur = 0;
    __syncthreads();   // tile 0 ready

    for (int kb = 0; kb < SS; kb += 64) {
        if (kb + 64 < SS) {
            const unsigned char* dst = sm + (cur ^ 1) * 32768;
            int ko = (kb + 64) * 2048;
            #pragma unroll
            for (int i = 0; i < 4; ++i) {
                gload16(K + srcK[i] + ko, (void*)(dst + ldsK[i]));
                gload16(V + srcV[i] + (kb + 64), (void*)(dst + ldsV[i]));
            }
        }
        const unsigned char* Kt = sm + cur * 32768;
        const unsigned char* Vt = Kt + 16384;

        // mask values for this lane's keys: key = kb2*32 + rg*8 + hi*4 + q4
        f32x4 mk[2][4];
        #pragma unroll
        for (int kb2 = 0; kb2 < 2; ++kb2)
            #pragma unroll
            for (int rg = 0; rg < 4; ++rg)
                mk[kb2][rg] = *(const f32x4*)(mb + kb + kb2 * 32 + rg * 8 + hi * 4);

        // S^T = K Q^T
        f32x16 sf0, sf1;
        #pragma unroll
        for (int j = 0; j < 16; ++j) { sf0[j] = 0.f; sf1[j] = 0.f; }
        __builtin_amdgcn_s_setprio(1);
        #pragma unroll
        for (int ks = 0; ks < 8; ++ks) {
            int row0 = qr, row1 = 32 + qr;
            int s0 = ((2 * ks + hi) ^ (row0 & 7));
            int s1 = ((2 * ks + hi) ^ (row1 & 7));
            bf16x8 kf0 = *(const bf16x8*)(Kt + row0 * 256 + s0 * 16);
            bf16x8 kf1 = *(const bf16x8*)(Kt + row1 * 256 + s1 * 16);
            sf0 = MFMA32(kf0, qf[ks], sf0);
            sf1 = MFMA32(kf1, qf[ks], sf1);
        }
        __builtin_amdgcn_s_setprio(0);

        // scale + mask (log2 domain)
        float sv[2][16];
        #pragma unroll
        for (int reg = 0; reg < 16; ++reg) {
            sv[0][reg] = sf0[reg] * SCL2 + mk[0][reg >> 2][reg & 3] * L2E;
            sv[1][reg] = sf1[reg] * SCL2 + mk[1][reg >> 2][reg & 3] * L2E;
        }

        // row max: balanced tree over 32 in-lane values, then cross-half permlane
        float mx[8];
        #pragma unroll
        for (int j = 0; j < 8; ++j)
            mx[j] = fmaxf(fmaxf(sv[0][2*j], sv[0][2*j+1]),
                          fmaxf(sv[1][2*j], sv[1][2*j+1]));
        float m01 = fmaxf(fmaxf(fmaxf(mx[0], mx[1]), fmaxf(mx[2], mx[3])),
                          fmaxf(fmaxf(mx[4], mx[5]), fmaxf(mx[6], mx[7])));
        float2 mp = xswap(m01);
        float mt = fmaxf(mp.x, mp.y);

        // defer-max
        float alpha = 1.f;
        int allskip = __all(mt <= mr + 8.f);
        if (!allskip) {
            float nm = fmaxf(mr, mt);
            alpha = __builtin_amdgcn_exp2f(mr - nm);
            mr = nm;
            #pragma unroll
            for (int dblk = 0; dblk < 4; ++dblk)
                #pragma unroll
                for (int reg = 0; reg < 16; ++reg)
                    acc[dblk][reg] *= alpha;
        }

        // P = exp2(S - m), row sum (4 partials), cross-half permlane
        float s0 = 0.f, s1 = 0.f, s2 = 0.f, s3 = 0.f;
        #pragma unroll
        for (int kb2 = 0; kb2 < 2; ++kb2)
            #pragma unroll
            for (int reg = 0; reg < 16; reg += 4) {
                float p0 = __builtin_amdgcn_exp2f(sv[kb2][reg + 0] - mr);
                float p1 = __builtin_amdgcn_exp2f(sv[kb2][reg + 1] - mr);
                float p2 = __builtin_amdgcn_exp2f(sv[kb2][reg + 2] - mr);
                float p3 = __builtin_amdgcn_exp2f(sv[kb2][reg + 3] - mr);
                sv[kb2][reg + 0] = p0; sv[kb2][reg + 1] = p1;
                sv[kb2][reg + 2] = p2; sv[kb2][reg + 3] = p3;
                s0 += p0; s1 += p1; s2 += p2; s3 += p3;
            }
        float rsl = (s0 + s1) + (s2 + s3);
        float2 rp = xswap(rsl);
        float rs = rp.x + rp.y;
        lr = lr * alpha + rs;

        // P -> PV B-fragments via permlane32_swap:
        // pswap(W00,W10): W00' = w[0] (both halves), W10' = w[2]. Same for W01/W11 -> w[1],w[3].
        bf16x8 pfr[4];
        #pragma unroll
        for (int kb16 = 0; kb16 < 4; ++kb16) {
            const int kb2 = kb16 >> 1, i2 = kb16 & 1;
            float* pv = sv[kb2];
            unsigned W00 = packbf(pv[(2*i2+0)*4 + 0], pv[(2*i2+0)*4 + 1]);
            unsigned W01 = packbf(pv[(2*i2+0)*4 + 2], pv[(2*i2+0)*4 + 3]);
            unsigned W10 = packbf(pv[(2*i2+1)*4 + 0], pv[(2*i2+1)*4 + 1]);
            unsigned W11 = packbf(pv[(2*i2+1)*4 + 2], pv[(2*i2+1)*4 + 3]);
            pswap(W00, W10);
            pswap(W01, W11);
            union { unsigned w[4]; bf16x8 v; } u;
            u.w[0] = W00; u.w[1] = W01; u.w[2] = W10; u.w[3] = W11;
            pfr[kb16] = u.v;
        }

        // O^T += V^T P^T
        __builtin_amdgcn_s_setprio(1);
        #pragma unroll
        for (int dblk = 0; dblk < 4; ++dblk) {
            int d = dblk * 32 + qr;
            f32x16 a = acc[dblk];
            #pragma unroll
            for (int kb16 = 0; kb16 < 4; ++kb16) {
                int s = ((2 * kb16 + hi) ^ (d & 7));
                bf16x8 vf = *(const bf16x8*)(Vt + d * 128 + s * 16);
                a = MFMA32(vf, pfr[kb16], a);
            }
            acc[dblk] = a;
        }
        __builtin_amdgcn_s_setprio(0);

        __syncthreads();
        cur ^= 1;
    }

    // epilogue: O[qrow][d], d = dblk*32 + rg*8 + 4*hi + q4; per-lane 1/l
    float linv = 1.f / lr;
    unsigned short* orow = O + (rowQ0 + qr) * 2048 + h * 128;
    #pragma unroll
    for (int dblk = 0; dblk < 4; ++dblk)
        #pragma unroll
        for (int rg = 0; rg < 4; ++rg) {
            float v0 = acc[dblk][rg * 4 + 0] * linv;
            float v1 = acc[dblk][rg * 4 + 1] * linv;
            float v2 = acc[dblk][rg * 4 + 2] * linv;
            float v3 = acc[dblk][rg * 4 + 3] * linv;
            uint2 o;
            o.x = packbf(v0, v1);
            o.y = packbf(v2, v3);
            *(uint2*)(orow + dblk * 32 + rg * 8 + hi * 4) = o;
        }
}

// ---------------- host launch ----------------
extern "C" void kernel_launch(void* const* d_in, const int* in_sizes, int n_in,
                              void* d_out, int out_size, void* d_ws, size_t ws_size,
                              hipStream_t stream)
{
    (void)in_sizes; (void)n_in; (void)out_size; (void)ws_size;
    const float* x    = (const float*)d_in[0];
    const float* mask = (const float*)d_in[1];
    const float* Wq   = (const float*)d_in[2];
    const float* bq   = (const float*)d_in[3];
    const float* Wk   = (const float*)d_in[4];
    const float* bk   = (const float*)d_in[5];
    const float* Wv   = (const float*)d_in[6];
    const float* bv   = (const float*)d_in[7];
    const float* Wo   = (const float*)d_in[8];
    const float* bo   = (const float*)d_in[9];
    float* out = (float*)d_out;

    char* ws = (char*)d_ws;
    unsigned short* xb  = (unsigned short*)(ws);                        // 16 MB
    unsigned short* Wqt = (unsigned short*)(ws + (16u << 20));          //  8 MB
    unsigned short* Wkt = (unsigned short*)(ws + (24u << 20));          //  8 MB
    unsigned short* Wvt = (unsigned short*)(ws + (32u << 20));          //  8 MB
    unsigned short* Wot = (unsigned short*)(ws + (40u << 20));          //  8 MB
    unsigned short* Qb  = (unsigned short*)(ws + (48u << 20));          // 16 MB
    unsigned short* Kb  = (unsigned short*)(ws + (64u << 20));          // 16 MB
    unsigned short* Vtb = (unsigned short*)(ws + (80u << 20));          // 16 MB
    unsigned short* Ab  = (unsigned short*)(ws + (16u << 20));          // 16 MB, reuses Wqt/Wkt

    cast_f32_bf16<<<2048, 256, 0, stream>>>(x, xb, MTOT * HHH);
    dim3 tb(32, 8), tg(64, 64);
    transpose_cast<<<tg, tb, 0, stream>>>(Wq, Wqt);
    transpose_cast<<<tg, tb, 0, stream>>>(Wk, Wkt);
    transpose_cast<<<tg, tb, 0, stream>>>(Wv, Wvt);
    transpose_cast<<<tg, tb, 0, stream>>>(Wo, Wot);

    dim3 gg(MTOT / 128, HHH / 128);  // (32, 16)
    gemm_bf16<0><<<gg, 256, 0, stream>>>(xb, Wqt, bq, Qb,  MTOT, HHH, HHH);
    gemm_bf16<0><<<gg, 256, 0, stream>>>(xb, Wkt, bk, Kb,  MTOT, HHH, HHH);
    gemm_bf16<1><<<gg, 256, 0, stream>>>(xb, Wvt, bv, Vtb, MTOT, HHH, HHH);

    attn_fwd<<<BB * NHH * (SS / 128), 256, 0, stream>>>(Qb, Kb, Vtb, mask, Ab);

    gemm_bf16<2><<<gg, 256, 0, stream>>>(Ab, Wot, bo, out, MTOT, HHH, HHH);
}

// Round 5
// 290.584 us; speedup vs baseline: 1.2764x; 1.0644x over previous
//
#include <hip/hip_runtime.h>
#include <hip/hip_bf16.h>
#include <stdint.h>

// Problem constants
#define BB   2
#define SS   2048
#define HHH  2048
#define NHH  16
#define HDD  128
#define MTOT 4096   // BB*SS

typedef __bf16 bf16x8 __attribute__((ext_vector_type(8)));
typedef float  f32x4  __attribute__((ext_vector_type(4)));
typedef float  f32x16 __attribute__((ext_vector_type(16)));

#define MFMA16(a, b, c) __builtin_amdgcn_mfma_f32_16x16x32_bf16((a), (b), (c), 0, 0, 0)
#define MFMA32(a, b, c) __builtin_amdgcn_mfma_f32_32x32x16_bf16((a), (b), (c), 0, 0, 0)

__device__ __forceinline__ unsigned short f2bf(float f) {
    union { float f; unsigned u; } v; v.f = f;
    unsigned r = v.u + 0x7FFFu + ((v.u >> 16) & 1u);   // RNE
    return (unsigned short)(r >> 16);
}

__device__ __forceinline__ unsigned packbf(float a, float b) {
    union { __bf16 h[2]; unsigned u; } p;
    p.h[0] = (__bf16)a; p.h[1] = (__bf16)b;
    return p.u;
}

// v_permlane32_swap_b32: a' = [a.lo32, b.lo32], b' = [a.hi32, b.hi32]
__device__ __forceinline__ void pswap(unsigned &a, unsigned &b) {
    asm("v_permlane32_swap_b32 %0, %1" : "+v"(a), "+v"(b));
}

// cross-half (lane ^ 32) pair: returns {own-half view, other-half view}
__device__ __forceinline__ float2 xswap(float x) {
    unsigned a = __builtin_bit_cast(unsigned, x);
    unsigned b;
    asm("v_mov_b32 %0, %1" : "=v"(b) : "v"(a));   // force distinct register
    asm("v_permlane32_swap_b32 %0, %1" : "+v"(a), "+v"(b));
    return make_float2(__builtin_bit_cast(float, a), __builtin_bit_cast(float, b));
}

// async global->LDS, 16B per lane. LDS dest is wave-uniform base + lane*16.
__device__ __forceinline__ void gload16(const void* src, void* lds) {
    __builtin_amdgcn_global_load_lds(
        (__attribute__((address_space(1))) void*)src,
        (__attribute__((address_space(3))) void*)lds,
        16, 0, 0);
}

// ---------------- cast f32 -> bf16 (vectorized) ----------------
__global__ void cast_f32_bf16(const float* __restrict__ in,
                              unsigned short* __restrict__ out, int n) {
    int i = (blockIdx.x * blockDim.x + threadIdx.x) * 4;
    int stride = gridDim.x * blockDim.x * 4;
    for (; i < n; i += stride) {
        float4 v = *(const float4*)(in + i);
        ushort4 o;
        o.x = f2bf(v.x); o.y = f2bf(v.y); o.z = f2bf(v.z); o.w = f2bf(v.w);
        *(ushort4*)(out + i) = o;
    }
}

// -------- transpose + cast all 4 weights: W (K x N f32) -> Wt (N x K bf16) --------
__global__ void transpose_cast4(const float* __restrict__ W0, const float* __restrict__ W1,
                                const float* __restrict__ W2, const float* __restrict__ W3,
                                unsigned short* __restrict__ out) {
    const float* in = blockIdx.z == 0 ? W0 : blockIdx.z == 1 ? W1 : blockIdx.z == 2 ? W2 : W3;
    unsigned short* o = out + (size_t)blockIdx.z * ((size_t)HHH * HHH);
    __shared__ float tile[32][33];
    int c0 = blockIdx.x * 32, r0 = blockIdx.y * 32;
    int tx = threadIdx.x, ty = threadIdx.y;   // (32, 8)
    #pragma unroll
    for (int i = 0; i < 32; i += 8)
        tile[ty + i][tx] = in[(size_t)(r0 + ty + i) * HHH + c0 + tx];
    __syncthreads();
    #pragma unroll
    for (int i = 0; i < 32; i += 8)
        o[(size_t)(c0 + ty + i) * HHH + r0 + tx] = f2bf(tile[tx][ty + i]);
}

// ---------------- 8-phase GEMM: C[M,N] = A[M,K] @ Bt[N,K]^T + bias ----------------
// BM=128, BN=256, BK=64. 8 waves (2M x 4N), per-wave 64x64 out, 512 threads.
// Triple-buffered LDS (3 x 48KB): 2-deep prefetch, counted vmcnt(6) at tile end.
// 4 phases/K-tile: {ds_read quadrant | 2 staging issues, barrier, lgkmcnt(0),
//                   setprio, 8 MFMA, setprio, barrier}.
// MODE 0: bf16 row-major out. MODE 1: bf16 per-head-transposed (V). MODE 2: f32 out.
template<int MODE>
__global__ __launch_bounds__(512, 2) void gemm8_bf16(
    const unsigned short* __restrict__ A,
    const unsigned short* __restrict__ Bt,
    const float* __restrict__ bias,
    void* __restrict__ Cout,
    int M, int N, int K)
{
    __shared__ __align__(16) unsigned char sm[147456];
    const int tid = threadIdx.x;
    const int wv = tid >> 6, ln = tid & 63;
    const int g = ln >> 4, r = ln & 15;
    const int wr = wv >> 2, wc = wv & 3;

    // XCD swizzle: 256 blocks, 32/XCD. XCD c owns n-column c (B panel L2-resident).
    const int bid = blockIdx.x;
    const int lb = (bid & 7) * 32 + (bid >> 3);
    const int m0 = (lb & 31) * 128;
    const int n0 = (lb >> 5) * 256;

    // staging precompute. Rows are 128B (64 bf16) = 8 granules of 16B.
    // phys granule = logical ^ (row & 7); source pre-swizzled, LDS linear.
    unsigned srcA[2]; int ldsA[2];
    #pragma unroll
    for (int j = 0; j < 2; ++j) {
        int o = j * 8192 + tid * 16;
        int row = o >> 7;
        int lg = ((o >> 4) & 7) ^ (row & 7);
        srcA[j] = (unsigned)(m0 + row) * K + lg * 8;
        ldsA[j] = o;
    }
    unsigned srcB[4]; int ldsB[4];
    #pragma unroll
    for (int j = 0; j < 4; ++j) {
        int o = j * 8192 + tid * 16;
        int row = o >> 7;
        int lg = ((o >> 4) & 7) ^ (row & 7);
        srcB[j] = (unsigned)(n0 + row) * K + lg * 8;
        ldsB[j] = 16384 + o;
    }

    f32x4 acc[4][4];
    #pragma unroll
    for (int i = 0; i < 4; ++i)
        #pragma unroll
        for (int j = 0; j < 4; ++j)
            acc[i][j] = (f32x4){0.f, 0.f, 0.f, 0.f};

    const int NT = K >> 6;   // 32

    // prologue: stage tiles 0 and 1 (6 issues each)
    {
        unsigned char* b0 = sm;
        unsigned char* b1 = sm + 49152;
        #pragma unroll
        for (int j = 0; j < 2; ++j) gload16(A + srcA[j], b0 + ldsA[j]);
        #pragma unroll
        for (int j = 0; j < 4; ++j) gload16(Bt + srcB[j], b0 + ldsB[j]);
        #pragma unroll
        for (int j = 0; j < 2; ++j) gload16(A + srcA[j] + 64, b1 + ldsA[j]);
        #pragma unroll
        for (int j = 0; j < 4; ++j) gload16(Bt + srcB[j] + 64, b1 + ldsB[j]);
    }
    asm volatile("s_waitcnt vmcnt(6)" ::: "memory");
    __builtin_amdgcn_s_barrier();

    int csel = 0;   // t % 3
    int psel = 2;   // (t+2) % 3
    for (int t = 0; t < NT; ++t) {
        const unsigned char* Ab = sm + csel * 49152;
        const unsigned char* Bb = Ab + 16384;
        unsigned char* Pb = sm + psel * 49152;
        const bool pre = (t + 2 < NT);
        const int ko = (t + 2) * 64;

        bf16x8 af[2][2], bf[2][2];
        // frag read helpers (all indices compile-time after unroll)
        #define LDA(mi, ks) (*(const bf16x8*)(Ab + (wr * 64 + (mi) * 16 + r) * 128 + \
                             ((((ks) << 2) + g) ^ ((wr * 64 + (mi) * 16 + r) & 7)) * 16))
        #define LDB(ni, ks) (*(const bf16x8*)(Bb + (wc * 64 + (ni) * 16 + r) * 128 + \
                             ((((ks) << 2) + g) ^ ((wc * 64 + (ni) * 16 + r) & 7)) * 16))

        // ---- phase 0: read A{0,1}, B{0,1}; stage B0,B1; MFMA (0,1)x(0,1)
        af[0][0] = LDA(0, 0); af[0][1] = LDA(0, 1);
        af[1][0] = LDA(1, 0); af[1][1] = LDA(1, 1);
        bf[0][0] = LDB(0, 0); bf[0][1] = LDB(0, 1);
        bf[1][0] = LDB(1, 0); bf[1][1] = LDB(1, 1);
        if (pre) { gload16(Bt + srcB[0] + ko, Pb + ldsB[0]);
                   gload16(Bt + srcB[1] + ko, Pb + ldsB[1]); }
        __builtin_amdgcn_s_barrier();
        asm volatile("s_waitcnt lgkmcnt(0)" ::: "memory");
        __builtin_amdgcn_s_setprio(1);
        #pragma unroll
        for (int mi = 0; mi < 2; ++mi)
            #pragma unroll
            for (int ni = 0; ni < 2; ++ni)
                #pragma unroll
                for (int ks = 0; ks < 2; ++ks)
                    acc[mi][ni] = MFMA16(af[mi][ks], bf[ni][ks], acc[mi][ni]);
        __builtin_amdgcn_s_setprio(0);
        __builtin_amdgcn_s_barrier();

        // ---- phase 1: read B{2,3}; stage B2,B3; MFMA (0,1)x(2,3) (A held)
        bf[0][0] = LDB(2, 0); bf[0][1] = LDB(2, 1);
        bf[1][0] = LDB(3, 0); bf[1][1] = LDB(3, 1);
        if (pre) { gload16(Bt + srcB[2] + ko, Pb + ldsB[2]);
                   gload16(Bt + srcB[3] + ko, Pb + ldsB[3]); }
        __builtin_amdgcn_s_barrier();
        asm volatile("s_waitcnt lgkmcnt(0)" ::: "memory");
        __builtin_amdgcn_s_setprio(1);
        #pragma unroll
        for (int mi = 0; mi < 2; ++mi)
            #pragma unroll
            for (int ni = 0; ni < 2; ++ni)
                #pragma unroll
                for (int ks = 0; ks < 2; ++ks)
                    acc[mi][ni + 2] = MFMA16(af[mi][ks], bf[ni][ks], acc[mi][ni + 2]);
        __builtin_amdgcn_s_setprio(0);
        __builtin_amdgcn_s_barrier();

        // ---- phase 2: read A{2,3}; stage A0,A1; MFMA (2,3)x(2,3) (B held)
        af[0][0] = LDA(2, 0); af[0][1] = LDA(2, 1);
        af[1][0] = LDA(3, 0); af[1][1] = LDA(3, 1);
        if (pre) { gload16(A + srcA[0] + ko, Pb + ldsA[0]);
                   gload16(A + srcA[1] + ko, Pb + ldsA[1]); }
        __builtin_amdgcn_s_barrier();
        asm volatile("s_waitcnt lgkmcnt(0)" ::: "memory");
        __builtin_amdgcn_s_setprio(1);
        #pragma unroll
        for (int mi = 0; mi < 2; ++mi)
            #pragma unroll
            for (int ni = 0; ni < 2; ++ni)
                #pragma unroll
                for (int ks = 0; ks < 2; ++ks)
                    acc[mi + 2][ni + 2] = MFMA16(af[mi][ks], bf[ni][ks], acc[mi + 2][ni + 2]);
        __builtin_amdgcn_s_setprio(0);
        __builtin_amdgcn_s_barrier();

        // ---- phase 3: read B{0,1}; MFMA (2,3)x(0,1) (A held)
        bf[0][0] = LDB(0, 0); bf[0][1] = LDB(0, 1);
        bf[1][0] = LDB(1, 0); bf[1][1] = LDB(1, 1);
        __builtin_amdgcn_s_barrier();
        asm volatile("s_waitcnt lgkmcnt(0)" ::: "memory");
        __builtin_amdgcn_s_setprio(1);
        #pragma unroll
        for (int mi = 0; mi < 2; ++mi)
            #pragma unroll
            for (int ni = 0; ni < 2; ++ni)
                #pragma unroll
                for (int ks = 0; ks < 2; ++ks)
                    acc[mi + 2][ni] = MFMA16(af[mi][ks], bf[ni][ks], acc[mi + 2][ni]);
        __builtin_amdgcn_s_setprio(0);
        __builtin_amdgcn_s_barrier();

        // tile end: counted wait — tile t+1's 6 loads are the oldest outstanding
        if (pre) asm volatile("s_waitcnt vmcnt(6)" ::: "memory");
        else     asm volatile("s_waitcnt vmcnt(0)" ::: "memory");
        __builtin_amdgcn_s_barrier();

        csel = (csel == 2) ? 0 : csel + 1;
        psel = (psel == 2) ? 0 : psel + 1;
        #undef LDA
        #undef LDB
    }

    // epilogue: C/D layout col = lane&15, row = 4*(lane>>4)+reg
    #pragma unroll
    for (int mt = 0; mt < 4; ++mt) {
        #pragma unroll
        for (int nt = 0; nt < 4; ++nt) {
            int col = n0 + wc * 64 + nt * 16 + r;
            float bvv = bias[col];
            f32x4 a = acc[mt][nt];
            int mrow = m0 + wr * 64 + mt * 16 + g * 4;
            if (MODE == 0) {
                #pragma unroll
                for (int q = 0; q < 4; ++q)
                    ((unsigned short*)Cout)[(size_t)(mrow + q) * N + col] = f2bf(a[q] + bvv);
            } else if (MODE == 2) {
                #pragma unroll
                for (int q = 0; q < 4; ++q)
                    ((float*)Cout)[(size_t)(mrow + q) * N + col] = a[q] + bvv;
            } else {
                int b = mrow >> 11, s0x = mrow & 2047;
                ushort4 o;
                o.x = f2bf(a[0] + bvv); o.y = f2bf(a[1] + bvv);
                o.z = f2bf(a[2] + bvv); o.w = f2bf(a[3] + bvv);
                *(ushort4*)((unsigned short*)Cout + ((size_t)(b * 2048 + col)) * 2048 + s0x) = o;
            }
        }
    }
}

// ---------------- flash attention, 32x32 MFMA, permlane cross-half ----------------
__global__ __launch_bounds__(256, 2) void attn_fwd(
    const unsigned short* __restrict__ Q,
    const unsigned short* __restrict__ K,
    const unsigned short* __restrict__ V,
    const float* __restrict__ mask,
    unsigned short* __restrict__ O)
{
    __shared__ __align__(16) unsigned char sm[65536];
    const int tid = threadIdx.x, wv = tid >> 6, ln = tid & 63;
    const int hi = ln >> 5, qr = ln & 31;

    // XCD-bijective swizzle (512 blocks = 8 XCD x 64)
    const int bid = blockIdx.x;
    const int lb = (bid & 7) * 64 + (bid >> 3);
    const int qb = lb & 15;
    const int bh = lb >> 4;
    const int h = bh & 15, b = bh >> 4;

    const size_t rowQ0 = (size_t)(b * 2048 + qb * 128 + wv * 32);
    const float SCL2 = 0.08838834764831845f * 1.4426950408889634f; // scale*log2e
    const float L2E  = 1.4426950408889634f;

    unsigned srcK[4], srcV[4];
    int ldsK[4], ldsV[4];
    #pragma unroll
    for (int i = 0; i < 4; ++i) {
        int ch = wv * 4 + i;
        int o = ch * 1024 + ln * 16;
        { int row = o >> 8; int gl = ((o >> 4) & 15) ^ (row & 7);
          srcK[i] = (unsigned)((b * 2048 + row) * 2048 + h * 128 + gl * 8);
          ldsK[i] = ch * 1024; }
        { int d = o >> 7; int gl = ((o >> 4) & 7) ^ (d & 7);
          srcV[i] = (unsigned)((b * 2048 + h * 128 + d) * 2048 + gl * 8);
          ldsV[i] = 16384 + ch * 1024; }
    }

    // stage tile 0 into buffer 0
    #pragma unroll
    for (int i = 0; i < 4; ++i) {
        gload16(K + srcK[i], sm + ldsK[i]);
        gload16(V + srcV[i], sm + ldsV[i]);
    }

    // Q fragments (B-operand): col = qr, k = hi*8+j, 8 k-steps of 16
    bf16x8 qf[8];
    #pragma unroll
    for (int ks = 0; ks < 8; ++ks)
        qf[ks] = *(const bf16x8*)(Q + (rowQ0 + qr) * 2048 + h * 128 + ks * 16 + hi * 8);

    f32x16 acc[4];
    #pragma unroll
    for (int i = 0; i < 4; ++i)
        #pragma unroll
        for (int j = 0; j < 16; ++j)
            acc[i][j] = 0.f;
    float mr = -3.0e38f, lr = 0.f;   // per-lane: q-row = qr

    const float* mb = mask + b * 2048;
    int cur = 0;
    __syncthreads();   // tile 0 ready

    for (int kb = 0; kb < SS; kb += 64) {
        if (kb + 64 < SS) {
            const unsigned char* dst = sm + (cur ^ 1) * 32768;
            int ko = (kb + 64) * 2048;
            #pragma unroll
            for (int i = 0; i < 4; ++i) {
                gload16(K + srcK[i] + ko, (void*)(dst + ldsK[i]));
                gload16(V + srcV[i] + (kb + 64), (void*)(dst + ldsV[i]));
            }
        }
        const unsigned char* Kt = sm + cur * 32768;
        const unsigned char* Vt = Kt + 16384;

        // mask values for this lane's keys: key = kb2*32 + rg*8 + hi*4 + q4
        f32x4 mk[2][4];
        #pragma unroll
        for (int kb2 = 0; kb2 < 2; ++kb2)
            #pragma unroll
            for (int rg = 0; rg < 4; ++rg)
                mk[kb2][rg] = *(const f32x4*)(mb + kb + kb2 * 32 + rg * 8 + hi * 4);

        // S^T = K Q^T
        f32x16 sf0, sf1;
        #pragma unroll
        for (int j = 0; j < 16; ++j) { sf0[j] = 0.f; sf1[j] = 0.f; }
        __builtin_amdgcn_s_setprio(1);
        #pragma unroll
        for (int ks = 0; ks < 8; ++ks) {
            int row0 = qr, row1 = 32 + qr;
            int s0 = ((2 * ks + hi) ^ (row0 & 7));
            int s1 = ((2 * ks + hi) ^ (row1 & 7));
            bf16x8 kf0 = *(const bf16x8*)(Kt + row0 * 256 + s0 * 16);
            bf16x8 kf1 = *(const bf16x8*)(Kt + row1 * 256 + s1 * 16);
            sf0 = MFMA32(kf0, qf[ks], sf0);
            sf1 = MFMA32(kf1, qf[ks], sf1);
        }
        __builtin_amdgcn_s_setprio(0);

        // scale + mask (log2 domain)
        float sv[2][16];
        #pragma unroll
        for (int reg = 0; reg < 16; ++reg) {
            sv[0][reg] = sf0[reg] * SCL2 + mk[0][reg >> 2][reg & 3] * L2E;
            sv[1][reg] = sf1[reg] * SCL2 + mk[1][reg >> 2][reg & 3] * L2E;
        }

        // row max: balanced tree over 32 in-lane values, then cross-half permlane
        float mx[8];
        #pragma unroll
        for (int j = 0; j < 8; ++j)
            mx[j] = fmaxf(fmaxf(sv[0][2*j], sv[0][2*j+1]),
                          fmaxf(sv[1][2*j], sv[1][2*j+1]));
        float m01 = fmaxf(fmaxf(fmaxf(mx[0], mx[1]), fmaxf(mx[2], mx[3])),
                          fmaxf(fmaxf(mx[4], mx[5]), fmaxf(mx[6], mx[7])));
        float2 mp = xswap(m01);
        float mt = fmaxf(mp.x, mp.y);

        // defer-max
        float alpha = 1.f;
        int allskip = __all(mt <= mr + 8.f);
        if (!allskip) {
            float nm = fmaxf(mr, mt);
            alpha = __builtin_amdgcn_exp2f(mr - nm);
            mr = nm;
            #pragma unroll
            for (int dblk = 0; dblk < 4; ++dblk)
                #pragma unroll
                for (int reg = 0; reg < 16; ++reg)
                    acc[dblk][reg] *= alpha;
        }

        // P = exp2(S - m), row sum (4 partials), cross-half permlane
        float s0 = 0.f, s1 = 0.f, s2 = 0.f, s3 = 0.f;
        #pragma unroll
        for (int kb2 = 0; kb2 < 2; ++kb2)
            #pragma unroll
            for (int reg = 0; reg < 16; reg += 4) {
                float p0 = __builtin_amdgcn_exp2f(sv[kb2][reg + 0] - mr);
                float p1 = __builtin_amdgcn_exp2f(sv[kb2][reg + 1] - mr);
                float p2 = __builtin_amdgcn_exp2f(sv[kb2][reg + 2] - mr);
                float p3 = __builtin_amdgcn_exp2f(sv[kb2][reg + 3] - mr);
                sv[kb2][reg + 0] = p0; sv[kb2][reg + 1] = p1;
                sv[kb2][reg + 2] = p2; sv[kb2][reg + 3] = p3;
                s0 += p0; s1 += p1; s2 += p2; s3 += p3;
            }
        float rsl = (s0 + s1) + (s2 + s3);
        float2 rp = xswap(rsl);
        float rs = rp.x + rp.y;
        lr = lr * alpha + rs;

        // P -> PV B-fragments via permlane32_swap
        bf16x8 pfr[4];
        #pragma unroll
        for (int kb16 = 0; kb16 < 4; ++kb16) {
            const int kb2 = kb16 >> 1, i2 = kb16 & 1;
            float* pv = sv[kb2];
            unsigned W00 = packbf(pv[(2*i2+0)*4 + 0], pv[(2*i2+0)*4 + 1]);
            unsigned W01 = packbf(pv[(2*i2+0)*4 + 2], pv[(2*i2+0)*4 + 3]);
            unsigned W10 = packbf(pv[(2*i2+1)*4 + 0], pv[(2*i2+1)*4 + 1]);
            unsigned W11 = packbf(pv[(2*i2+1)*4 + 2], pv[(2*i2+1)*4 + 3]);
            pswap(W00, W10);
            pswap(W01, W11);
            union { unsigned w[4]; bf16x8 v; } u;
            u.w[0] = W00; u.w[1] = W01; u.w[2] = W10; u.w[3] = W11;
            pfr[kb16] = u.v;
        }

        // O^T += V^T P^T
        __builtin_amdgcn_s_setprio(1);
        #pragma unroll
        for (int dblk = 0; dblk < 4; ++dblk) {
            int d = dblk * 32 + qr;
            f32x16 a = acc[dblk];
            #pragma unroll
            for (int kb16 = 0; kb16 < 4; ++kb16) {
                int s = ((2 * kb16 + hi) ^ (d & 7));
                bf16x8 vf = *(const bf16x8*)(Vt + d * 128 + s * 16);
                a = MFMA32(vf, pfr[kb16], a);
            }
            acc[dblk] = a;
        }
        __builtin_amdgcn_s_setprio(0);

        __syncthreads();
        cur ^= 1;
    }

    // epilogue: O[qrow][d], d = dblk*32 + rg*8 + 4*hi + q4; per-lane 1/l
    float linv = 1.f / lr;
    unsigned short* orow = O + (rowQ0 + qr) * 2048 + h * 128;
    #pragma unroll
    for (int dblk = 0; dblk < 4; ++dblk)
        #pragma unroll
        for (int rg = 0; rg < 4; ++rg) {
            float v0 = acc[dblk][rg * 4 + 0] * linv;
            float v1 = acc[dblk][rg * 4 + 1] * linv;
            float v2 = acc[dblk][rg * 4 + 2] * linv;
            float v3 = acc[dblk][rg * 4 + 3] * linv;
            uint2 o;
            o.x = packbf(v0, v1);
            o.y = packbf(v2, v3);
            *(uint2*)(orow + dblk * 32 + rg * 8 + hi * 4) = o;
        }
}

// ---------------- host launch ----------------
extern "C" void kernel_launch(void* const* d_in, const int* in_sizes, int n_in,
                              void* d_out, int out_size, void* d_ws, size_t ws_size,
                              hipStream_t stream)
{
    (void)in_sizes; (void)n_in; (void)out_size; (void)ws_size;
    const float* x    = (const float*)d_in[0];
    const float* mask = (const float*)d_in[1];
    const float* Wq   = (const float*)d_in[2];
    const float* bq   = (const float*)d_in[3];
    const float* Wk   = (const float*)d_in[4];
    const float* bk   = (const float*)d_in[5];
    const float* Wv   = (const float*)d_in[6];
    const float* bv   = (const float*)d_in[7];
    const float* Wo   = (const float*)d_in[8];
    const float* bo   = (const float*)d_in[9];
    float* out = (float*)d_out;

    char* ws = (char*)d_ws;
    unsigned short* xb  = (unsigned short*)(ws);                        // 16 MB
    unsigned short* Wqt = (unsigned short*)(ws + (16u << 20));          //  8 MB (Wqt..Wot contiguous)
    unsigned short* Wkt = (unsigned short*)(ws + (24u << 20));
    unsigned short* Wvt = (unsigned short*)(ws + (32u << 20));
    unsigned short* Wot = (unsigned short*)(ws + (40u << 20));
    unsigned short* Qb  = (unsigned short*)(ws + (48u << 20));          // 16 MB
    unsigned short* Kb  = (unsigned short*)(ws + (64u << 20));          // 16 MB
    unsigned short* Vtb = (unsigned short*)(ws + (80u << 20));          // 16 MB
    unsigned short* Ab  = (unsigned short*)(ws + (16u << 20));          // 16 MB, reuses Wqt/Wkt (dead by then)

    cast_f32_bf16<<<2048, 256, 0, stream>>>(x, xb, MTOT * HHH);
    transpose_cast4<<<dim3(64, 64, 4), dim3(32, 8), 0, stream>>>(Wq, Wk, Wv, Wo, Wqt);

    gemm8_bf16<0><<<256, 512, 0, stream>>>(xb, Wqt, bq, Qb,  MTOT, HHH, HHH);
    gemm8_bf16<0><<<256, 512, 0, stream>>>(xb, Wkt, bk, Kb,  MTOT, HHH, HHH);
    gemm8_bf16<1><<<256, 512, 0, stream>>>(xb, Wvt, bv, Vtb, MTOT, HHH, HHH);

    attn_fwd<<<BB * NHH * (SS / 128), 256, 0, stream>>>(Qb, Kb, Vtb, mask, Ab);

    gemm8_bf16<2><<<256, 512, 0, stream>>>(Ab, Wot, bo, out, MTOT, HHH, HHH);
}